// Round 6
// baseline (51.569 us; speedup 1.0000x reference)
//
#include <hip/hip_runtime.h>
#include <hip/hip_fp16.h>
#include <math.h>

#define NVIEW 3
#define HLOW 256
#define WLOW 256
#define NPIX (HLOW * WLOW)
#define NS 64
#define VOLN 128
#define IMGH 512
#define IMGW 512
#define BLK 256
#define BLOCKS_PER_VIEW (NPIX / BLK)   // 256 (one block per low-res row)
#define NVOX (VOLN * VOLN * VOLN)      // 2097152
#define UPS2_BLOCKS ((NVIEW * IMGH * IMGW / 2) / BLK) // 1536 (2 px per thread)

// ---------------- per-ray setup (shared) ----------------
struct Ray {
    float gx0, gxs, gy0, gys, gz0, gzs;  // grid coords affine in z
    float zlo, zhi;                      // outside-unit-sphere z interval
    float z0, zstep, ncz;
};

__device__ __forceinline__ Ray ray_setup(
    int view, int row, int col,
    const float* __restrict__ intrs, const float* __restrict__ c2ws,
    const float* __restrict__ nf)
{
    const float px = 511.0f * (float)col * (1.0f / 255.0f);
    const float py = 511.0f * (float)row * (1.0f / 255.0f);

    const float* K = intrs + view * 9;
    const float a = K[0], b = K[1], c = K[2];
    const float d = K[3], e = K[4], f = K[5];
    const float g = K[6], h = K[7], i9 = K[8];
    const float det = a * (e * i9 - f * h) - b * (d * i9 - f * g) + c * (d * h - e * g);
    const float id = 1.0f / det;
    const float m00 = (e * i9 - f * h) * id, m01 = -(b * i9 - c * h) * id, m02 = (b * f - c * e) * id;
    const float m10 = -(d * i9 - f * g) * id, m11 = (a * i9 - c * g) * id, m12 = -(a * f - c * d) * id;
    const float m20 = (d * h - e * g) * id, m21 = -(a * h - b * g) * id, m22 = (a * e - b * d) * id;

    const float cx = m00 * px + m01 * py + m02;
    const float cy = m10 * px + m11 * py + m12;
    const float cz = m20 * px + m21 * py + m22;
    const float inr = rsqrtf(cx * cx + cy * cy + cz * cz);
    const float ncx = cx * inr, ncy = cy * inr, ncz = cz * inr;

    const float* M = c2ws + view * 16;
    const float dx = M[0] * ncx + M[1] * ncy + M[2] * ncz;
    const float dy = M[4] * ncx + M[5] * ncy + M[6] * ncz;
    const float dz = M[8] * ncx + M[9] * ncy + M[10] * ncz;
    const float tx = M[3], ty = M[7], tz = M[11];

    Ray r;
    r.gx0 = (tx + 1.0f) * 63.5f; r.gxs = dx * 63.5f;
    r.gy0 = (ty + 1.0f) * 63.5f; r.gys = dy * 63.5f;
    r.gz0 = (tz + 1.0f) * 63.5f; r.gzs = dz * 63.5f;

    const float bq = tx * dx + ty * dy + tz * dz;
    const float cq = tx * tx + ty * ty + tz * tz;
    const float disc = bq * bq - (cq - 1.0f);
    if (disc >= 0.0f) {
        const float rt = sqrtf(disc);
        r.zlo = -bq - rt;
        r.zhi = -bq + rt;
    } else {
        r.zlo = 3.4e38f;
        r.zhi = 0.0f;
    }

    r.z0 = nf[view * 2 + 0];
    r.zstep = (nf[view * 2 + 1] - r.z0) * (1.0f / 63.0f);
    r.ncz = ncz;
    return r;
}

// ---------------- corner-fetch variants ----------------
struct C8 { float2 p00, p01, p10, p11; }; // p{z}{y} = (x0, x1)

__device__ __forceinline__ C8 fetch_quad(const void* Fv, unsigned off) {
    const uint4 q = reinterpret_cast<const uint4*>(Fv)[off];
    union { unsigned u; __half2 h; } a;
    C8 c;
    a.u = q.x; c.p00 = __half22float2(a.h);
    a.u = q.y; c.p01 = __half22float2(a.h);
    a.u = q.z; c.p10 = __half22float2(a.h);
    a.u = q.w; c.p11 = __half22float2(a.h);
    return c;
}

__device__ __forceinline__ C8 fetch_pair(const void* Fv, unsigned off) {
    const uint2 q0 = reinterpret_cast<const uint2*>(Fv)[off];
    const uint2 q1 = reinterpret_cast<const uint2*>(Fv)[off + VOLN * VOLN];
    union { unsigned u; __half2 h; } a;
    C8 c;
    a.u = q0.x; c.p00 = __half22float2(a.h);
    a.u = q0.y; c.p01 = __half22float2(a.h);
    a.u = q1.x; c.p10 = __half22float2(a.h);
    a.u = q1.y; c.p11 = __half22float2(a.h);
    return c;
}

__device__ __forceinline__ C8 fetch_f32(const void* Fv, unsigned off) {
    const float* p0 = reinterpret_cast<const float*>(Fv) + off;
    C8 c;
    c.p00 = *reinterpret_cast<const float2*>(p0);
    c.p01 = *reinterpret_cast<const float2*>(p0 + VOLN);
    c.p10 = *reinterpret_cast<const float2*>(p0 + VOLN * VOLN);
    c.p11 = *reinterpret_cast<const float2*>(p0 + VOLN * VOLN + VOLN);
    return c;
}

// ---------------- build kernels (per-launch, deterministic) ----------------
// F[z][y][x] = f16 x8: all 8 corners of cell (x..x+1, y..y+1, z..z+1), clamped.
__global__ __launch_bounds__(BLK) void build_quad_kernel(
    const float* __restrict__ vol, uint4* __restrict__ F)
{
    const int id = blockIdx.x * BLK + threadIdx.x;
    const int x = id & 127;
    const int y = (id >> 7) & 127;
    const int z = id >> 14;
    const int xp = min(x + 1, 127);
    const int yp = min(y + 1, 127);
    const int zp = min(z + 1, 127);
    const float* r00 = vol + (z * VOLN + y) * VOLN;
    const float* r01 = vol + (z * VOLN + yp) * VOLN;
    const float* r10 = vol + (zp * VOLN + y) * VOLN;
    const float* r11 = vol + (zp * VOLN + yp) * VOLN;
    const __half2 h0 = __floats2half2_rn(r00[x], r00[xp]);
    const __half2 h1 = __floats2half2_rn(r01[x], r01[xp]);
    const __half2 h2 = __floats2half2_rn(r10[x], r10[xp]);
    const __half2 h3 = __floats2half2_rn(r11[x], r11[xp]);
    uint4 o;
    o.x = *reinterpret_cast<const unsigned*>(&h0);
    o.y = *reinterpret_cast<const unsigned*>(&h1);
    o.z = *reinterpret_cast<const unsigned*>(&h2);
    o.w = *reinterpret_cast<const unsigned*>(&h3);
    F[id] = o;
}

// P[z][y][x] = f16 x4: the 2x2 (y,x) corners at this z (z handled by 2 loads).
__global__ __launch_bounds__(BLK) void build_pair_kernel(
    const float* __restrict__ vol, uint2* __restrict__ P)
{
    const int id = blockIdx.x * BLK + threadIdx.x;
    const int x = id & 127;
    const int y = (id >> 7) & 127;
    const int z = id >> 14;
    const int xp = min(x + 1, 127);
    const int yp = min(y + 1, 127);
    const float* r0 = vol + (z * VOLN + y) * VOLN;
    const float* r1 = vol + (z * VOLN + yp) * VOLN;
    const __half2 h0 = __floats2half2_rn(r0[x], r0[xp]);
    const __half2 h1 = __floats2half2_rn(r1[x], r1[xp]);
    uint2 o;
    o.x = *reinterpret_cast<const unsigned*>(&h0);
    o.y = *reinterpret_cast<const unsigned*>(&h1);
    P[id] = o;
}

// ---------------- raymarch (MODE: 0=quad f16, 1=pair f16, 2=f32 direct) ----
// Block = one full 256-px image row; wave = 64 consecutive cols. Lanes are
// x-adjacent so each quad gather touches ~9 contiguous 128B lines (minimum).
template <int MODE>
__global__ __launch_bounds__(BLK) void raymarch_kernel(
    const float* __restrict__ intrs, const float* __restrict__ c2ws,
    const float* __restrict__ nf, const void* __restrict__ Fv,
    float* __restrict__ depth_low, float* __restrict__ partials)
{
    const int view = blockIdx.x >> 8;
    const int row  = blockIdx.x & 255;
    const int t    = threadIdx.x;
    const int col  = t;

    const Ray r = ray_setup(view, row, col, intrs, c2ws, nf);

    float lsum = 0.0f, zacc = 0.0f;
    float d6 = 0.0f, dout = 0.0f, cnt = 0.0f;

    #pragma unroll 16
    for (int s = 0; s < NS; ++s) {
        const float z = fmaf(r.zstep, (float)s, r.z0);
        float gx = fmaf(r.gxs, z, r.gx0);
        float gy = fmaf(r.gys, z, r.gy0);
        float gz = fmaf(r.gzs, z, r.gz0);
        gx = fminf(fmaxf(gx, 0.0f), 127.0f);
        gy = fminf(fmaxf(gy, 0.0f), 127.0f);
        gz = fminf(fmaxf(gz, 0.0f), 127.0f);

        const int xb = min((int)gx, VOLN - 2);
        const int yb = min((int)gy, VOLN - 2);
        const int zb = min((int)gz, VOLN - 2);
        const float fx = gx - (float)xb;
        const float fy = gy - (float)yb;
        const float fz = gz - (float)zb;

        const unsigned off = ((unsigned)zb << 14) + ((unsigned)yb << 7) + (unsigned)xb;
        const C8 cc = (MODE == 0) ? fetch_quad(Fv, off)
                    : (MODE == 1) ? fetch_pair(Fv, off)
                                  : fetch_f32(Fv, off);

        const float c00 = fmaf(fx, cc.p00.y - cc.p00.x, cc.p00.x);
        const float c01 = fmaf(fx, cc.p01.y - cc.p01.x, cc.p01.x);
        const float c10 = fmaf(fx, cc.p10.y - cc.p10.x, cc.p10.x);
        const float c11 = fmaf(fx, cc.p11.y - cc.p11.x, cc.p11.x);
        const float c0 = fmaf(fy, c01 - c00, c00);
        const float c1 = fmaf(fy, c11 - c10, c10);
        const float dens = fmaf(fz, c1 - c0, c0);

        const float w = __expf(dens);
        lsum += w;
        zacc = fmaf(z, w, zacc);

        if (s < 6) d6 += dens;
        const bool o = (z < r.zlo) || (z > r.zhi);
        dout += o ? dens : 0.0f;
        cnt  += o ? 1.0f : 0.0f;
    }

    depth_low[view * NPIX + row * WLOW + col] = (zacc / lsum) * r.ncz;

    __shared__ float s0[BLK], s1[BLK], s2[BLK];
    s0[t] = d6; s1[t] = dout; s2[t] = cnt;
    __syncthreads();
    for (int off = BLK / 2; off > 0; off >>= 1) {
        if (t < off) {
            s0[t] += s0[t + off];
            s1[t] += s1[t + off];
            s2[t] += s2[t + off];
        }
        __syncthreads();
    }
    if (t == 0) {
        partials[blockIdx.x * 3 + 0] = s0[0];
        partials[blockIdx.x * 3 + 1] = s1[0];
        partials[blockIdx.x * 3 + 2] = s2[0];
    }
}

// ---------------- fused epilogue: upsample (2 px/thread) + occ reduce ----
__global__ __launch_bounds__(BLK) void epilogue_kernel(
    const float* __restrict__ low, const float* __restrict__ partials,
    float* __restrict__ out)
{
    if (blockIdx.x >= UPS2_BLOCKS) {
        const int view = blockIdx.x - UPS2_BLOCKS;
        const int t = threadIdx.x;
        __shared__ float s0[BLK], s1[BLK], s2[BLK];
        const int bi = view * BLOCKS_PER_VIEW + t; // BLOCKS_PER_VIEW == BLK
        s0[t] = partials[bi * 3 + 0];
        s1[t] = partials[bi * 3 + 1];
        s2[t] = partials[bi * 3 + 2];
        __syncthreads();
        for (int off = BLK / 2; off > 0; off >>= 1) {
            if (t < off) {
                s0[t] += s0[t + off];
                s1[t] += s1[t + off];
                s2[t] += s2[t + off];
            }
            __syncthreads();
        }
        if (t == 0) {
            out[NVIEW * IMGH * IMGW + view] =
                s0[0] * (1.0f / (float)(NPIX * 6)) + s1[0] / (s2[0] + 1e-10f);
        }
        return;
    }

    // 2 consecutive output pixels per thread, float2 store
    const int idx2 = blockIdx.x * BLK + threadIdx.x;
    const int view = idx2 / (IMGH * IMGW / 2);
    const int rem  = idx2 - view * (IMGH * IMGW / 2);
    const int rr = rem >> 8;         // output row
    const int cp = rem & 255;        // column pair
    const int cc0 = cp * 2;

    const float sy = (float)rr * 0.5f - 0.25f;
    const float y0f = floorf(sy);
    const float wy = sy - y0f;
    const int y0 = (int)y0f;
    const int y0c = max(y0, 0), y1c = min(y0 + 1, HLOW - 1);
    const float* src = low + view * NPIX;
    const float* r0 = src + y0c * WLOW;
    const float* r1 = src + y1c * WLOW;

    float2 res;
    {
        const float sx = (float)cc0 * 0.5f - 0.25f;
        const float x0f = floorf(sx);
        const float wx = sx - x0f;
        const int x0 = (int)x0f;
        const int x0c = max(x0, 0), x1c = min(x0 + 1, WLOW - 1);
        const float top = r0[x0c] * (1.0f - wx) + r0[x1c] * wx;
        const float bot = r1[x0c] * (1.0f - wx) + r1[x1c] * wx;
        res.x = top * (1.0f - wy) + bot * wy;
    }
    {
        const int cc1 = cc0 + 1;
        const float sx = (float)cc1 * 0.5f - 0.25f;
        const float x0f = floorf(sx);
        const float wx = sx - x0f;
        const int x0 = (int)x0f;
        const int x0c = max(x0, 0), x1c = min(x0 + 1, WLOW - 1);
        const float top = r0[x0c] * (1.0f - wx) + r0[x1c] * wx;
        const float bot = r1[x0c] * (1.0f - wx) + r1[x1c] * wx;
        res.y = top * (1.0f - wy) + bot * wy;
    }
    *reinterpret_cast<float2*>(out + view * (IMGH * IMGW) + rr * IMGW + cc0) = res;
}

extern "C" void kernel_launch(void* const* d_in, const int* in_sizes, int n_in,
                              void* d_out, int out_size, void* d_ws, size_t ws_size,
                              hipStream_t stream) {
    // input order: imgs, intrs, c2ws, near_fars, density_volume, stage_idx
    const float* intrs = (const float*)d_in[1];
    const float* c2ws  = (const float*)d_in[2];
    const float* nf    = (const float*)d_in[3];
    const float* vol   = (const float*)d_in[4];
    float* out = (float*)d_out;

    const size_t quad_bytes  = (size_t)NVOX * 16;
    const size_t pair_bytes  = (size_t)NVOX * 8;
    const size_t depth_bytes = (size_t)NVIEW * NPIX * 4;
    const size_t part_bytes  = (size_t)NVIEW * BLOCKS_PER_VIEW * 3 * 4;
    char* ws = (char*)d_ws;

    float* depth_low;
    float* partials;

    if (ws_size >= quad_bytes + depth_bytes + part_bytes) {
        uint4* F = (uint4*)ws;
        depth_low = (float*)(ws + quad_bytes);
        partials  = depth_low + NVIEW * NPIX;
        build_quad_kernel<<<NVOX / BLK, BLK, 0, stream>>>(vol, F);
        raymarch_kernel<0><<<NVIEW * BLOCKS_PER_VIEW, BLK, 0, stream>>>(
            intrs, c2ws, nf, (const void*)F, depth_low, partials);
    } else if (ws_size >= pair_bytes + depth_bytes + part_bytes) {
        uint2* P = (uint2*)ws;
        depth_low = (float*)(ws + pair_bytes);
        partials  = depth_low + NVIEW * NPIX;
        build_pair_kernel<<<NVOX / BLK, BLK, 0, stream>>>(vol, P);
        raymarch_kernel<1><<<NVIEW * BLOCKS_PER_VIEW, BLK, 0, stream>>>(
            intrs, c2ws, nf, (const void*)P, depth_low, partials);
    } else {
        depth_low = (float*)ws;
        partials  = depth_low + NVIEW * NPIX;
        raymarch_kernel<2><<<NVIEW * BLOCKS_PER_VIEW, BLK, 0, stream>>>(
            intrs, c2ws, nf, (const void*)vol, depth_low, partials);
    }

    epilogue_kernel<<<UPS2_BLOCKS + NVIEW, BLK, 0, stream>>>(depth_low, partials, out);
}

// Round 7
// 50.387 us; speedup vs baseline: 1.0235x; 1.0235x over previous
//
#include <hip/hip_runtime.h>
#include <hip/hip_fp16.h>
#include <math.h>

#define NVIEW 3
#define HLOW 256
#define WLOW 256
#define NPIX (HLOW * WLOW)
#define NS 64
#define VOLN 128
#define IMGH 512
#define IMGW 512
#define BLK 256
#define BLOCKS_PER_VIEW (NPIX / BLK)   // 256 (one block per low-res row)
#define NVOX (VOLN * VOLN * VOLN)      // 2097152
#define UPS2_BLOCKS ((NVIEW * IMGH * IMGW / 2) / BLK) // 1536 (2 px per thread)
#define NXCD 8
#define MARCH_BLOCKS (NVIEW * BLOCKS_PER_VIEW)        // 768
#define CHUNK (MARCH_BLOCKS / NXCD)                   // 96

// ---------------- per-ray setup (shared) ----------------
struct Ray {
    float gx0, gxs, gy0, gys, gz0, gzs;  // grid coords affine in z
    float zlo, zhi;                      // outside-unit-sphere z interval
    float z0, zstep, ncz;
};

__device__ __forceinline__ Ray ray_setup(
    int view, int row, int col,
    const float* __restrict__ intrs, const float* __restrict__ c2ws,
    const float* __restrict__ nf)
{
    const float px = 511.0f * (float)col * (1.0f / 255.0f);
    const float py = 511.0f * (float)row * (1.0f / 255.0f);

    const float* K = intrs + view * 9;
    const float a = K[0], b = K[1], c = K[2];
    const float d = K[3], e = K[4], f = K[5];
    const float g = K[6], h = K[7], i9 = K[8];
    const float det = a * (e * i9 - f * h) - b * (d * i9 - f * g) + c * (d * h - e * g);
    const float id = 1.0f / det;
    const float m00 = (e * i9 - f * h) * id, m01 = -(b * i9 - c * h) * id, m02 = (b * f - c * e) * id;
    const float m10 = -(d * i9 - f * g) * id, m11 = (a * i9 - c * g) * id, m12 = -(a * f - c * d) * id;
    const float m20 = (d * h - e * g) * id, m21 = -(a * h - b * g) * id, m22 = (a * e - b * d) * id;

    const float cx = m00 * px + m01 * py + m02;
    const float cy = m10 * px + m11 * py + m12;
    const float cz = m20 * px + m21 * py + m22;
    const float inr = rsqrtf(cx * cx + cy * cy + cz * cz);
    const float ncx = cx * inr, ncy = cy * inr, ncz = cz * inr;

    const float* M = c2ws + view * 16;
    const float dx = M[0] * ncx + M[1] * ncy + M[2] * ncz;
    const float dy = M[4] * ncx + M[5] * ncy + M[6] * ncz;
    const float dz = M[8] * ncx + M[9] * ncy + M[10] * ncz;
    const float tx = M[3], ty = M[7], tz = M[11];

    Ray r;
    r.gx0 = (tx + 1.0f) * 63.5f; r.gxs = dx * 63.5f;
    r.gy0 = (ty + 1.0f) * 63.5f; r.gys = dy * 63.5f;
    r.gz0 = (tz + 1.0f) * 63.5f; r.gzs = dz * 63.5f;

    const float bq = tx * dx + ty * dy + tz * dz;
    const float cq = tx * tx + ty * ty + tz * tz;
    const float disc = bq * bq - (cq - 1.0f);
    if (disc >= 0.0f) {
        const float rt = sqrtf(disc);
        r.zlo = -bq - rt;
        r.zhi = -bq + rt;
    } else {
        r.zlo = 3.4e38f;
        r.zhi = 0.0f;
    }

    r.z0 = nf[view * 2 + 0];
    r.zstep = (nf[view * 2 + 1] - r.z0) * (1.0f / 63.0f);
    r.ncz = ncz;
    return r;
}

// ---------------- corner-fetch variants (fallback modes) ----------------
struct C8 { float2 p00, p01, p10, p11; }; // p{z}{y} = (x0, x1)

__device__ __forceinline__ C8 fetch_pair(const void* Fv, unsigned off) {
    const uint2 q0 = reinterpret_cast<const uint2*>(Fv)[off];
    const uint2 q1 = reinterpret_cast<const uint2*>(Fv)[off + VOLN * VOLN];
    union { unsigned u; __half2 h; } a;
    C8 c;
    a.u = q0.x; c.p00 = __half22float2(a.h);
    a.u = q0.y; c.p01 = __half22float2(a.h);
    a.u = q1.x; c.p10 = __half22float2(a.h);
    a.u = q1.y; c.p11 = __half22float2(a.h);
    return c;
}

__device__ __forceinline__ C8 fetch_f32(const void* Fv, unsigned off) {
    const float* p0 = reinterpret_cast<const float*>(Fv) + off;
    C8 c;
    c.p00 = *reinterpret_cast<const float2*>(p0);
    c.p01 = *reinterpret_cast<const float2*>(p0 + VOLN);
    c.p10 = *reinterpret_cast<const float2*>(p0 + VOLN * VOLN);
    c.p11 = *reinterpret_cast<const float2*>(p0 + VOLN * VOLN + VOLN);
    return c;
}

// ---------------- build kernels (per-launch, deterministic) ----------------
// F[z][y][x] = f16 x8: all 8 corners of cell (x..x+1, y..y+1, z..z+1), clamped.
__global__ __launch_bounds__(BLK) void build_quad_kernel(
    const float* __restrict__ vol, uint4* __restrict__ F)
{
    const int id = blockIdx.x * BLK + threadIdx.x;
    const int x = id & 127;
    const int y = (id >> 7) & 127;
    const int z = id >> 14;
    const int xp = min(x + 1, 127);
    const int yp = min(y + 1, 127);
    const int zp = min(z + 1, 127);
    const float* r00 = vol + (z * VOLN + y) * VOLN;
    const float* r01 = vol + (z * VOLN + yp) * VOLN;
    const float* r10 = vol + (zp * VOLN + y) * VOLN;
    const float* r11 = vol + (zp * VOLN + yp) * VOLN;
    const __half2 h0 = __floats2half2_rn(r00[x], r00[xp]);
    const __half2 h1 = __floats2half2_rn(r01[x], r01[xp]);
    const __half2 h2 = __floats2half2_rn(r10[x], r10[xp]);
    const __half2 h3 = __floats2half2_rn(r11[x], r11[xp]);
    uint4 o;
    o.x = *reinterpret_cast<const unsigned*>(&h0);
    o.y = *reinterpret_cast<const unsigned*>(&h1);
    o.z = *reinterpret_cast<const unsigned*>(&h2);
    o.w = *reinterpret_cast<const unsigned*>(&h3);
    F[id] = o;
}

// P[z][y][x] = f16 x4: the 2x2 (y,x) corners at this z (z handled by 2 loads).
__global__ __launch_bounds__(BLK) void build_pair_kernel(
    const float* __restrict__ vol, uint2* __restrict__ P)
{
    const int id = blockIdx.x * BLK + threadIdx.x;
    const int x = id & 127;
    const int y = (id >> 7) & 127;
    const int z = id >> 14;
    const int xp = min(x + 1, 127);
    const int yp = min(y + 1, 127);
    const float* r0 = vol + (z * VOLN + y) * VOLN;
    const float* r1 = vol + (z * VOLN + yp) * VOLN;
    const __half2 h0 = __floats2half2_rn(r0[x], r0[xp]);
    const __half2 h1 = __floats2half2_rn(r1[x], r1[xp]);
    uint2 o;
    o.x = *reinterpret_cast<const unsigned*>(&h0);
    o.y = *reinterpret_cast<const unsigned*>(&h1);
    P[id] = o;
}

// ---------------- raymarch MODE 0: quad f16, batched loads, XCD swizzle ----
// Block = one full 256-px image row (lanes x-adjacent -> minimal line
// footprint per gather). Bijective XCD swizzle gives each XCD 96 consecutive
// (view,row) blocks -> compact voxel wedge -> L2-resident working set.
// 8-deep explicit load batching guarantees MLP past the accumulate chain.
__global__ __launch_bounds__(BLK) void raymarch_quad_kernel(
    const float* __restrict__ intrs, const float* __restrict__ c2ws,
    const float* __restrict__ nf, const uint4* __restrict__ F,
    float* __restrict__ depth_low, float* __restrict__ partials)
{
    const int wg  = blockIdx.x;
    const int swz = (wg & (NXCD - 1)) * CHUNK + (wg >> 3); // bijective, 768=8*96
    const int view = swz >> 8;
    const int row  = swz & 255;
    const int t    = threadIdx.x;
    const int col  = t;

    const Ray r = ray_setup(view, row, col, intrs, c2ws, nf);

    float lsum = 0.0f, zacc = 0.0f;
    float d6 = 0.0f, dout = 0.0f, cnt = 0.0f;

    for (int sb = 0; sb < NS; sb += 8) {
        unsigned offs[8];
        float fxs[8], fys[8], fzs[8], zs[8];

        #pragma unroll
        for (int i = 0; i < 8; ++i) {
            const float z = fmaf(r.zstep, (float)(sb + i), r.z0);
            zs[i] = z;
            float gx = fmaf(r.gxs, z, r.gx0);
            float gy = fmaf(r.gys, z, r.gy0);
            float gz = fmaf(r.gzs, z, r.gz0);
            gx = fminf(fmaxf(gx, 0.0f), 127.0f);
            gy = fminf(fmaxf(gy, 0.0f), 127.0f);
            gz = fminf(fmaxf(gz, 0.0f), 127.0f);
            const int xb = min((int)gx, VOLN - 2);
            const int yb = min((int)gy, VOLN - 2);
            const int zb = min((int)gz, VOLN - 2);
            fxs[i] = gx - (float)xb;
            fys[i] = gy - (float)yb;
            fzs[i] = gz - (float)zb;
            offs[i] = ((unsigned)zb << 14) + ((unsigned)yb << 7) + (unsigned)xb;
        }

        uint4 q[8];
        #pragma unroll
        for (int i = 0; i < 8; ++i) q[i] = F[offs[i]];

        #pragma unroll
        for (int i = 0; i < 8; ++i) {
            union { unsigned u; __half2 h; } a;
            float2 p00, p01, p10, p11;
            a.u = q[i].x; p00 = __half22float2(a.h);
            a.u = q[i].y; p01 = __half22float2(a.h);
            a.u = q[i].z; p10 = __half22float2(a.h);
            a.u = q[i].w; p11 = __half22float2(a.h);

            const float fx = fxs[i], fy = fys[i], fz = fzs[i];
            const float c00 = fmaf(fx, p00.y - p00.x, p00.x);
            const float c01 = fmaf(fx, p01.y - p01.x, p01.x);
            const float c10 = fmaf(fx, p10.y - p10.x, p10.x);
            const float c11 = fmaf(fx, p11.y - p11.x, p11.x);
            const float c0 = fmaf(fy, c01 - c00, c00);
            const float c1 = fmaf(fy, c11 - c10, c10);
            const float dens = fmaf(fz, c1 - c0, c0);

            const float w = __expf(dens);
            lsum += w;
            zacc = fmaf(zs[i], w, zacc);

            if (sb == 0 && i < 6) d6 += dens;   // compile-time predicate
            const bool o = (zs[i] < r.zlo) || (zs[i] > r.zhi);
            dout += o ? dens : 0.0f;
            cnt  += o ? 1.0f : 0.0f;
        }
    }

    depth_low[view * NPIX + row * WLOW + col] = (zacc / lsum) * r.ncz;

    __shared__ float s0[BLK], s1[BLK], s2[BLK];
    s0[t] = d6; s1[t] = dout; s2[t] = cnt;
    __syncthreads();
    for (int off = BLK / 2; off > 0; off >>= 1) {
        if (t < off) {
            s0[t] += s0[t + off];
            s1[t] += s1[t + off];
            s2[t] += s2[t + off];
        }
        __syncthreads();
    }
    if (t == 0) {
        // partials indexed by the LOGICAL block (swz), not wg
        partials[swz * 3 + 0] = s0[0];
        partials[swz * 3 + 1] = s1[0];
        partials[swz * 3 + 2] = s2[0];
    }
}

// ---------------- raymarch fallback (MODE 1=pair f16, 2=f32 direct) ----
template <int MODE>
__global__ __launch_bounds__(BLK) void raymarch_kernel(
    const float* __restrict__ intrs, const float* __restrict__ c2ws,
    const float* __restrict__ nf, const void* __restrict__ Fv,
    float* __restrict__ depth_low, float* __restrict__ partials)
{
    const int view = blockIdx.x >> 8;
    const int row  = blockIdx.x & 255;
    const int t    = threadIdx.x;
    const int col  = t;

    const Ray r = ray_setup(view, row, col, intrs, c2ws, nf);

    float lsum = 0.0f, zacc = 0.0f;
    float d6 = 0.0f, dout = 0.0f, cnt = 0.0f;

    #pragma unroll 16
    for (int s = 0; s < NS; ++s) {
        const float z = fmaf(r.zstep, (float)s, r.z0);
        float gx = fmaf(r.gxs, z, r.gx0);
        float gy = fmaf(r.gys, z, r.gy0);
        float gz = fmaf(r.gzs, z, r.gz0);
        gx = fminf(fmaxf(gx, 0.0f), 127.0f);
        gy = fminf(fmaxf(gy, 0.0f), 127.0f);
        gz = fminf(fmaxf(gz, 0.0f), 127.0f);

        const int xb = min((int)gx, VOLN - 2);
        const int yb = min((int)gy, VOLN - 2);
        const int zb = min((int)gz, VOLN - 2);
        const float fx = gx - (float)xb;
        const float fy = gy - (float)yb;
        const float fz = gz - (float)zb;

        const unsigned off = ((unsigned)zb << 14) + ((unsigned)yb << 7) + (unsigned)xb;
        const C8 cc = (MODE == 1) ? fetch_pair(Fv, off) : fetch_f32(Fv, off);

        const float c00 = fmaf(fx, cc.p00.y - cc.p00.x, cc.p00.x);
        const float c01 = fmaf(fx, cc.p01.y - cc.p01.x, cc.p01.x);
        const float c10 = fmaf(fx, cc.p10.y - cc.p10.x, cc.p10.x);
        const float c11 = fmaf(fx, cc.p11.y - cc.p11.x, cc.p11.x);
        const float c0 = fmaf(fy, c01 - c00, c00);
        const float c1 = fmaf(fy, c11 - c10, c10);
        const float dens = fmaf(fz, c1 - c0, c0);

        const float w = __expf(dens);
        lsum += w;
        zacc = fmaf(z, w, zacc);

        if (s < 6) d6 += dens;
        const bool o = (z < r.zlo) || (z > r.zhi);
        dout += o ? dens : 0.0f;
        cnt  += o ? 1.0f : 0.0f;
    }

    depth_low[view * NPIX + row * WLOW + col] = (zacc / lsum) * r.ncz;

    __shared__ float s0[BLK], s1[BLK], s2[BLK];
    s0[t] = d6; s1[t] = dout; s2[t] = cnt;
    __syncthreads();
    for (int off = BLK / 2; off > 0; off >>= 1) {
        if (t < off) {
            s0[t] += s0[t + off];
            s1[t] += s1[t + off];
            s2[t] += s2[t + off];
        }
        __syncthreads();
    }
    if (t == 0) {
        partials[blockIdx.x * 3 + 0] = s0[0];
        partials[blockIdx.x * 3 + 1] = s1[0];
        partials[blockIdx.x * 3 + 2] = s2[0];
    }
}

// ---------------- fused epilogue: upsample (2 px/thread) + occ reduce ----
__global__ __launch_bounds__(BLK) void epilogue_kernel(
    const float* __restrict__ low, const float* __restrict__ partials,
    float* __restrict__ out)
{
    if (blockIdx.x >= UPS2_BLOCKS) {
        const int view = blockIdx.x - UPS2_BLOCKS;
        const int t = threadIdx.x;
        __shared__ float s0[BLK], s1[BLK], s2[BLK];
        const int bi = view * BLOCKS_PER_VIEW + t; // BLOCKS_PER_VIEW == BLK
        s0[t] = partials[bi * 3 + 0];
        s1[t] = partials[bi * 3 + 1];
        s2[t] = partials[bi * 3 + 2];
        __syncthreads();
        for (int off = BLK / 2; off > 0; off >>= 1) {
            if (t < off) {
                s0[t] += s0[t + off];
                s1[t] += s1[t + off];
                s2[t] += s2[t + off];
            }
            __syncthreads();
        }
        if (t == 0) {
            out[NVIEW * IMGH * IMGW + view] =
                s0[0] * (1.0f / (float)(NPIX * 6)) + s1[0] / (s2[0] + 1e-10f);
        }
        return;
    }

    // 2 consecutive output pixels per thread, float2 store
    const int idx2 = blockIdx.x * BLK + threadIdx.x;
    const int view = idx2 / (IMGH * IMGW / 2);
    const int rem  = idx2 - view * (IMGH * IMGW / 2);
    const int rr = rem >> 8;         // output row
    const int cp = rem & 255;        // column pair
    const int cc0 = cp * 2;

    const float sy = (float)rr * 0.5f - 0.25f;
    const float y0f = floorf(sy);
    const float wy = sy - y0f;
    const int y0 = (int)y0f;
    const int y0c = max(y0, 0), y1c = min(y0 + 1, HLOW - 1);
    const float* src = low + view * NPIX;
    const float* r0 = src + y0c * WLOW;
    const float* r1 = src + y1c * WLOW;

    float2 res;
    {
        const float sx = (float)cc0 * 0.5f - 0.25f;
        const float x0f = floorf(sx);
        const float wx = sx - x0f;
        const int x0 = (int)x0f;
        const int x0c = max(x0, 0), x1c = min(x0 + 1, WLOW - 1);
        const float top = r0[x0c] * (1.0f - wx) + r0[x1c] * wx;
        const float bot = r1[x0c] * (1.0f - wx) + r1[x1c] * wx;
        res.x = top * (1.0f - wy) + bot * wy;
    }
    {
        const int cc1 = cc0 + 1;
        const float sx = (float)cc1 * 0.5f - 0.25f;
        const float x0f = floorf(sx);
        const float wx = sx - x0f;
        const int x0 = (int)x0f;
        const int x0c = max(x0, 0), x1c = min(x0 + 1, WLOW - 1);
        const float top = r0[x0c] * (1.0f - wx) + r0[x1c] * wx;
        const float bot = r1[x0c] * (1.0f - wx) + r1[x1c] * wx;
        res.y = top * (1.0f - wy) + bot * wy;
    }
    *reinterpret_cast<float2*>(out + view * (IMGH * IMGW) + rr * IMGW + cc0) = res;
}

extern "C" void kernel_launch(void* const* d_in, const int* in_sizes, int n_in,
                              void* d_out, int out_size, void* d_ws, size_t ws_size,
                              hipStream_t stream) {
    // input order: imgs, intrs, c2ws, near_fars, density_volume, stage_idx
    const float* intrs = (const float*)d_in[1];
    const float* c2ws  = (const float*)d_in[2];
    const float* nf    = (const float*)d_in[3];
    const float* vol   = (const float*)d_in[4];
    float* out = (float*)d_out;

    const size_t quad_bytes  = (size_t)NVOX * 16;
    const size_t pair_bytes  = (size_t)NVOX * 8;
    const size_t depth_bytes = (size_t)NVIEW * NPIX * 4;
    const size_t part_bytes  = (size_t)NVIEW * BLOCKS_PER_VIEW * 3 * 4;
    char* ws = (char*)d_ws;

    float* depth_low;
    float* partials;

    if (ws_size >= quad_bytes + depth_bytes + part_bytes) {
        uint4* F = (uint4*)ws;
        depth_low = (float*)(ws + quad_bytes);
        partials  = depth_low + NVIEW * NPIX;
        build_quad_kernel<<<NVOX / BLK, BLK, 0, stream>>>(vol, F);
        raymarch_quad_kernel<<<MARCH_BLOCKS, BLK, 0, stream>>>(
            intrs, c2ws, nf, F, depth_low, partials);
    } else if (ws_size >= pair_bytes + depth_bytes + part_bytes) {
        uint2* P = (uint2*)ws;
        depth_low = (float*)(ws + pair_bytes);
        partials  = depth_low + NVIEW * NPIX;
        build_pair_kernel<<<NVOX / BLK, BLK, 0, stream>>>(vol, P);
        raymarch_kernel<1><<<MARCH_BLOCKS, BLK, 0, stream>>>(
            intrs, c2ws, nf, (const void*)P, depth_low, partials);
    } else {
        depth_low = (float*)ws;
        partials  = depth_low + NVIEW * NPIX;
        raymarch_kernel<2><<<MARCH_BLOCKS, BLK, 0, stream>>>(
            intrs, c2ws, nf, (const void*)vol, depth_low, partials);
    }

    epilogue_kernel<<<UPS2_BLOCKS + NVIEW, BLK, 0, stream>>>(depth_low, partials, out);
}

// Round 8
// 42.224 us; speedup vs baseline: 1.2213x; 1.1933x over previous
//
#include <hip/hip_runtime.h>
#include <hip/hip_fp16.h>
#include <math.h>

#define NVIEW 3
#define HLOW 256
#define WLOW 256
#define NPIX (HLOW * WLOW)
#define NS 64
#define VOLN 128
#define IMGH 512
#define IMGW 512
#define BLK 256
#define BLOCKS_PER_VIEW (NPIX / BLK)   // 256 (one block per low-res row)
#define NVOX (VOLN * VOLN * VOLN)      // 2097152
#define UPS2_BLOCKS ((NVIEW * IMGH * IMGW / 2) / BLK) // 1536 (2 px per thread)
#define NXCD 8
#define MARCH_BLOCKS (NVIEW * BLOCKS_PER_VIEW)        // 768
#define CHUNK (MARCH_BLOCKS / NXCD)                   // 96

// ---------------- per-ray setup: everything affine in SAMPLE INDEX s ------
struct Ray {
    float ax0, axs, ay0, ays, az0, azs;  // grid coords affine in s
    float sLo, sHi;                      // outside-sphere bounds in s-space
    float z0, zstep, ncz;
};

__device__ __forceinline__ Ray ray_setup(
    int view, int row, int col,
    const float* __restrict__ intrs, const float* __restrict__ c2ws,
    const float* __restrict__ nf)
{
    const float px = 511.0f * (float)col * (1.0f / 255.0f);
    const float py = 511.0f * (float)row * (1.0f / 255.0f);

    const float* K = intrs + view * 9;
    const float a = K[0], b = K[1], c = K[2];
    const float d = K[3], e = K[4], f = K[5];
    const float g = K[6], h = K[7], i9 = K[8];
    const float det = a * (e * i9 - f * h) - b * (d * i9 - f * g) + c * (d * h - e * g);
    const float id = 1.0f / det;
    const float m00 = (e * i9 - f * h) * id, m01 = -(b * i9 - c * h) * id, m02 = (b * f - c * e) * id;
    const float m10 = -(d * i9 - f * g) * id, m11 = (a * i9 - c * g) * id, m12 = -(a * f - c * d) * id;
    const float m20 = (d * h - e * g) * id, m21 = -(a * h - b * g) * id, m22 = (a * e - b * d) * id;

    const float cx = m00 * px + m01 * py + m02;
    const float cy = m10 * px + m11 * py + m12;
    const float cz = m20 * px + m21 * py + m22;
    const float inr = rsqrtf(cx * cx + cy * cy + cz * cz);
    const float ncx = cx * inr, ncy = cy * inr, ncz = cz * inr;

    const float* M = c2ws + view * 16;
    const float dx = M[0] * ncx + M[1] * ncy + M[2] * ncz;
    const float dy = M[4] * ncx + M[5] * ncy + M[6] * ncz;
    const float dz = M[8] * ncx + M[9] * ncy + M[10] * ncz;
    const float tx = M[3], ty = M[7], tz = M[11];

    const float z0 = nf[view * 2 + 0];
    const float zstep = (nf[view * 2 + 1] - z0) * (1.0f / 63.0f);

    Ray r;
    // g(z) = ((t + d z) + 1) * 63.5 ; z = z0 + zstep * s  ->  affine in s
    const float gx0 = (tx + 1.0f) * 63.5f, gxs = dx * 63.5f;
    const float gy0 = (ty + 1.0f) * 63.5f, gys = dy * 63.5f;
    const float gz0 = (tz + 1.0f) * 63.5f, gzs = dz * 63.5f;
    r.ax0 = fmaf(gxs, z0, gx0); r.axs = gxs * zstep;
    r.ay0 = fmaf(gys, z0, gy0); r.ays = gys * zstep;
    r.az0 = fmaf(gzs, z0, gz0); r.azs = gzs * zstep;

    // outside-unit-sphere interval in z, mapped to s-space
    const float bq = tx * dx + ty * dy + tz * dz;
    const float cq = tx * tx + ty * ty + tz * tz;
    const float disc = bq * bq - (cq - 1.0f);
    if (disc >= 0.0f) {
        const float rt = sqrtf(disc);
        const float inv = 1.0f / zstep;
        r.sLo = (-bq - rt - z0) * inv;
        r.sHi = (-bq + rt - z0) * inv;
    } else {                 // never enters the sphere: always outside
        r.sLo = 3.4e38f;
        r.sHi = 0.0f;
    }

    r.z0 = z0;
    r.zstep = zstep;
    r.ncz = ncz;
    return r;
}

// ---------------- build: z-paired f16 quad table ----------------
// F[z][y][x] = uint4; word k = __half2 (corner@z0, corner@z1):
//   w0=(c000,c100) w1=(c001,c101) w2=(c010,c110) w3=(c011,c111)
__global__ __launch_bounds__(BLK) void build_quad_kernel(
    const float* __restrict__ vol, uint4* __restrict__ F)
{
    const int id = blockIdx.x * BLK + threadIdx.x;
    const int x = id & 127;
    const int y = (id >> 7) & 127;
    const int z = id >> 14;
    const int yp = min(y + 1, 127);
    const int zp = min(z + 1, 127);
    const int xb = min(x, 126);
    const int sel = x - xb;      // 0 or 1; x==127 -> both corners = v.y

    const float2 v00 = *reinterpret_cast<const float2*>(vol + (z  * VOLN + y ) * VOLN + xb);
    const float2 v01 = *reinterpret_cast<const float2*>(vol + (z  * VOLN + yp) * VOLN + xb);
    const float2 v10 = *reinterpret_cast<const float2*>(vol + (zp * VOLN + y ) * VOLN + xb);
    const float2 v11 = *reinterpret_cast<const float2*>(vol + (zp * VOLN + yp) * VOLN + xb);

    const float c000 = sel ? v00.y : v00.x, c001 = v00.y;
    const float c010 = sel ? v01.y : v01.x, c011 = v01.y;
    const float c100 = sel ? v10.y : v10.x, c101 = v10.y;
    const float c110 = sel ? v11.y : v11.x, c111 = v11.y;

    const __half2 w0 = __floats2half2_rn(c000, c100);
    const __half2 w1 = __floats2half2_rn(c001, c101);
    const __half2 w2 = __floats2half2_rn(c010, c110);
    const __half2 w3 = __floats2half2_rn(c011, c111);
    uint4 o;
    o.x = *reinterpret_cast<const unsigned*>(&w0);
    o.y = *reinterpret_cast<const unsigned*>(&w1);
    o.z = *reinterpret_cast<const unsigned*>(&w2);
    o.w = *reinterpret_cast<const unsigned*>(&w3);
    F[id] = o;
}

// ---------------- raymarch: quad f16, packed lerp, batched, XCD swizzle ----
__global__ __launch_bounds__(BLK) void raymarch_quad_kernel(
    const float* __restrict__ intrs, const float* __restrict__ c2ws,
    const float* __restrict__ nf, const uint4* __restrict__ F,
    float* __restrict__ depth_low, float* __restrict__ partials)
{
    const int wg  = blockIdx.x;
    const int swz = (wg & (NXCD - 1)) * CHUNK + (wg >> 3); // bijective, 768=8*96
    const int view = swz >> 8;
    const int row  = swz & 255;
    const int t    = threadIdx.x;

    const Ray r = ray_setup(view, row, t, intrs, c2ws, nf);

    float lsum = 0.0f, sacc = 0.0f;
    float d6 = 0.0f, dout = 0.0f, cnt = 0.0f;

    for (int sb = 0; sb < NS; sb += 8) {
        unsigned offs[8];
        float fxs[8], fys[8], fzs[8];

        #pragma unroll
        for (int i = 0; i < 8; ++i) {
            const float sf = (float)(sb + i);
            float gx = fmaf(r.axs, sf, r.ax0);
            float gy = fmaf(r.ays, sf, r.ay0);
            float gz = fmaf(r.azs, sf, r.az0);
            gx = fminf(fmaxf(gx, 0.0f), 127.0f);
            gy = fminf(fmaxf(gy, 0.0f), 127.0f);
            gz = fminf(fmaxf(gz, 0.0f), 127.0f);
            const float xbf = fminf(floorf(gx), 126.0f);
            const float ybf = fminf(floorf(gy), 126.0f);
            const float zbf = fminf(floorf(gz), 126.0f);
            fxs[i] = gx - xbf;
            fys[i] = gy - ybf;
            fzs[i] = gz - zbf;
            offs[i] = (unsigned)fmaf(zbf, 16384.0f, fmaf(ybf, 128.0f, xbf));
        }

        uint4 q[8];
        #pragma unroll
        for (int i = 0; i < 8; ++i) q[i] = F[offs[i]];

        #pragma unroll
        for (int i = 0; i < 8; ++i) {
            const float sf = (float)(sb + i);
            union { unsigned u; __half2 h; } a0, a1, b0, b1;
            a0.u = q[i].x; a1.u = q[i].y; b0.u = q[i].z; b1.u = q[i].w;

            const __half2 fxh = __float2half2_rn(fxs[i]);
            const __half2 fyh = __float2half2_rn(fys[i]);
            // packed lerps do both z-layers at once
            const __half2 cx0 = __hfma2(fxh, __hsub2(a1.h, a0.h), a0.h);
            const __half2 cx1 = __hfma2(fxh, __hsub2(b1.h, b0.h), b0.h);
            const __half2 cy  = __hfma2(fyh, __hsub2(cx1, cx0), cx0);
            const float c0 = __low2float(cy);
            const float c1 = __high2float(cy);
            const float dens = fmaf(fzs[i], c1 - c0, c0);

            const float w = __expf(dens);
            lsum += w;
            sacc = fmaf(sf, w, sacc);

            if (sb == 0 && i < 6) d6 += dens;          // compile-time predicate
            const bool o = (sf < r.sLo) || (sf > r.sHi);
            dout += o ? dens : 0.0f;
            cnt  += o ? 1.0f : 0.0f;
        }
    }

    depth_low[view * NPIX + row * WLOW + t] =
        fmaf(r.zstep, sacc / lsum, r.z0) * r.ncz;

    __shared__ float s0[BLK], s1[BLK], s2[BLK];
    s0[t] = d6; s1[t] = dout; s2[t] = cnt;
    __syncthreads();
    for (int off = BLK / 2; off > 0; off >>= 1) {
        if (t < off) {
            s0[t] += s0[t + off];
            s1[t] += s1[t + off];
            s2[t] += s2[t + off];
        }
        __syncthreads();
    }
    if (t == 0) {
        partials[swz * 3 + 0] = s0[0];   // logical block index
        partials[swz * 3 + 1] = s1[0];
        partials[swz * 3 + 2] = s2[0];
    }
}

// ---------------- fallback raymarch: f32 volume direct (tiny ws) ----------
__global__ __launch_bounds__(BLK) void raymarch_f32_kernel(
    const float* __restrict__ intrs, const float* __restrict__ c2ws,
    const float* __restrict__ nf, const float* __restrict__ vol,
    float* __restrict__ depth_low, float* __restrict__ partials)
{
    const int view = blockIdx.x >> 8;
    const int row  = blockIdx.x & 255;
    const int t    = threadIdx.x;

    const Ray r = ray_setup(view, row, t, intrs, c2ws, nf);

    float lsum = 0.0f, sacc = 0.0f;
    float d6 = 0.0f, dout = 0.0f, cnt = 0.0f;

    #pragma unroll 16
    for (int s = 0; s < NS; ++s) {
        const float sf = (float)s;
        float gx = fmaf(r.axs, sf, r.ax0);
        float gy = fmaf(r.ays, sf, r.ay0);
        float gz = fmaf(r.azs, sf, r.az0);
        gx = fminf(fmaxf(gx, 0.0f), 127.0f);
        gy = fminf(fmaxf(gy, 0.0f), 127.0f);
        gz = fminf(fmaxf(gz, 0.0f), 127.0f);
        const float xbf = fminf(floorf(gx), 126.0f);
        const float ybf = fminf(floorf(gy), 126.0f);
        const float zbf = fminf(floorf(gz), 126.0f);
        const float fx = gx - xbf, fy = gy - ybf, fz = gz - zbf;
        const unsigned off = (unsigned)fmaf(zbf, 16384.0f, fmaf(ybf, 128.0f, xbf));

        const float* p0 = vol + off;
        const float2 v00 = *reinterpret_cast<const float2*>(p0);
        const float2 v01 = *reinterpret_cast<const float2*>(p0 + VOLN);
        const float2 v10 = *reinterpret_cast<const float2*>(p0 + VOLN * VOLN);
        const float2 v11 = *reinterpret_cast<const float2*>(p0 + VOLN * VOLN + VOLN);

        const float c00 = fmaf(fx, v00.y - v00.x, v00.x);
        const float c01 = fmaf(fx, v01.y - v01.x, v01.x);
        const float c10 = fmaf(fx, v10.y - v10.x, v10.x);
        const float c11 = fmaf(fx, v11.y - v11.x, v11.x);
        const float c0 = fmaf(fy, c01 - c00, c00);
        const float c1 = fmaf(fy, c11 - c10, c10);
        const float dens = fmaf(fz, c1 - c0, c0);

        const float w = __expf(dens);
        lsum += w;
        sacc = fmaf(sf, w, sacc);

        if (s < 6) d6 += dens;
        const bool o = (sf < r.sLo) || (sf > r.sHi);
        dout += o ? dens : 0.0f;
        cnt  += o ? 1.0f : 0.0f;
    }

    depth_low[view * NPIX + row * WLOW + t] =
        fmaf(r.zstep, sacc / lsum, r.z0) * r.ncz;

    __shared__ float s0[BLK], s1[BLK], s2[BLK];
    s0[t] = d6; s1[t] = dout; s2[t] = cnt;
    __syncthreads();
    for (int off = BLK / 2; off > 0; off >>= 1) {
        if (t < off) {
            s0[t] += s0[t + off];
            s1[t] += s1[t + off];
            s2[t] += s2[t + off];
        }
        __syncthreads();
    }
    if (t == 0) {
        partials[blockIdx.x * 3 + 0] = s0[0];
        partials[blockIdx.x * 3 + 1] = s1[0];
        partials[blockIdx.x * 3 + 2] = s2[0];
    }
}

// ---------------- fused epilogue: upsample (2 px/thread) + occ reduce ----
__global__ __launch_bounds__(BLK) void epilogue_kernel(
    const float* __restrict__ low, const float* __restrict__ partials,
    float* __restrict__ out)
{
    if (blockIdx.x >= UPS2_BLOCKS) {
        const int view = blockIdx.x - UPS2_BLOCKS;
        const int t = threadIdx.x;
        __shared__ float s0[BLK], s1[BLK], s2[BLK];
        const int bi = view * BLOCKS_PER_VIEW + t; // BLOCKS_PER_VIEW == BLK
        s0[t] = partials[bi * 3 + 0];
        s1[t] = partials[bi * 3 + 1];
        s2[t] = partials[bi * 3 + 2];
        __syncthreads();
        for (int off = BLK / 2; off > 0; off >>= 1) {
            if (t < off) {
                s0[t] += s0[t + off];
                s1[t] += s1[t + off];
                s2[t] += s2[t + off];
            }
            __syncthreads();
        }
        if (t == 0) {
            out[NVIEW * IMGH * IMGW + view] =
                s0[0] * (1.0f / (float)(NPIX * 6)) + s1[0] / (s2[0] + 1e-10f);
        }
        return;
    }

    const int idx2 = blockIdx.x * BLK + threadIdx.x;
    const int view = idx2 / (IMGH * IMGW / 2);
    const int rem  = idx2 - view * (IMGH * IMGW / 2);
    const int rr = rem >> 8;
    const int cp = rem & 255;
    const int cc0 = cp * 2;

    const float sy = (float)rr * 0.5f - 0.25f;
    const float y0f = floorf(sy);
    const float wy = sy - y0f;
    const int y0 = (int)y0f;
    const int y0c = max(y0, 0), y1c = min(y0 + 1, HLOW - 1);
    const float* src = low + view * NPIX;
    const float* r0 = src + y0c * WLOW;
    const float* r1 = src + y1c * WLOW;

    float2 res;
    {
        const float sx = (float)cc0 * 0.5f - 0.25f;
        const float x0f = floorf(sx);
        const float wx = sx - x0f;
        const int x0 = (int)x0f;
        const int x0c = max(x0, 0), x1c = min(x0 + 1, WLOW - 1);
        const float top = r0[x0c] * (1.0f - wx) + r0[x1c] * wx;
        const float bot = r1[x0c] * (1.0f - wx) + r1[x1c] * wx;
        res.x = top * (1.0f - wy) + bot * wy;
    }
    {
        const int cc1 = cc0 + 1;
        const float sx = (float)cc1 * 0.5f - 0.25f;
        const float x0f = floorf(sx);
        const float wx = sx - x0f;
        const int x0 = (int)x0f;
        const int x0c = max(x0, 0), x1c = min(x0 + 1, WLOW - 1);
        const float top = r0[x0c] * (1.0f - wx) + r0[x1c] * wx;
        const float bot = r1[x0c] * (1.0f - wx) + r1[x1c] * wx;
        res.y = top * (1.0f - wy) + bot * wy;
    }
    *reinterpret_cast<float2*>(out + view * (IMGH * IMGW) + rr * IMGW + cc0) = res;
}

extern "C" void kernel_launch(void* const* d_in, const int* in_sizes, int n_in,
                              void* d_out, int out_size, void* d_ws, size_t ws_size,
                              hipStream_t stream) {
    // input order: imgs, intrs, c2ws, near_fars, density_volume, stage_idx
    const float* intrs = (const float*)d_in[1];
    const float* c2ws  = (const float*)d_in[2];
    const float* nf    = (const float*)d_in[3];
    const float* vol   = (const float*)d_in[4];
    float* out = (float*)d_out;

    const size_t quad_bytes  = (size_t)NVOX * 16;
    const size_t depth_bytes = (size_t)NVIEW * NPIX * 4;
    const size_t part_bytes  = (size_t)NVIEW * BLOCKS_PER_VIEW * 3 * 4;
    char* ws = (char*)d_ws;

    float* depth_low;
    float* partials;

    if (ws_size >= quad_bytes + depth_bytes + part_bytes) {
        uint4* F = (uint4*)ws;
        depth_low = (float*)(ws + quad_bytes);
        partials  = depth_low + NVIEW * NPIX;
        build_quad_kernel<<<NVOX / BLK, BLK, 0, stream>>>(vol, F);
        raymarch_quad_kernel<<<MARCH_BLOCKS, BLK, 0, stream>>>(
            intrs, c2ws, nf, F, depth_low, partials);
    } else {
        depth_low = (float*)ws;
        partials  = depth_low + NVIEW * NPIX;
        raymarch_f32_kernel<<<MARCH_BLOCKS, BLK, 0, stream>>>(
            intrs, c2ws, nf, vol, depth_low, partials);
    }

    epilogue_kernel<<<UPS2_BLOCKS + NVIEW, BLK, 0, stream>>>(depth_low, partials, out);
}

// Round 9
// 37.438 us; speedup vs baseline: 1.3775x; 1.1278x over previous
//
#include <hip/hip_runtime.h>
#include <hip/hip_fp16.h>
#include <math.h>

#define NVIEW 3
#define HLOW 256
#define WLOW 256
#define NPIX (HLOW * WLOW)
#define NS 64
#define VOLN 128
#define IMGH 512
#define IMGW 512
#define BLK 256
#define BLOCKS_PER_VIEW (NPIX / BLK)   // 256 (one block per low-res row)
#define NVOX (VOLN * VOLN * VOLN)      // 2097152
#define UPS2_BLOCKS ((NVIEW * IMGH * IMGW / 2) / BLK) // 1536 (2 px per thread)
#define NXCD 8
#define MARCH_BLOCKS (NVIEW * BLOCKS_PER_VIEW)        // 768
#define CHUNK (MARCH_BLOCKS / NXCD)                   // 96

#define LOG2E     1.4426950408889634f
#define INV_LOG2E 0.6931471805599453f

// ---------------- per-ray setup: everything affine in SAMPLE INDEX s ------
struct Ray {
    float ax0, axs, ay0, ays, az0, azs;  // grid coords affine in s
    float sLo, sHi;                      // outside-sphere bounds in s-space
    float z0, zstep, ncz;
};

__device__ __forceinline__ Ray ray_setup(
    int view, int row, int col,
    const float* __restrict__ intrs, const float* __restrict__ c2ws,
    const float* __restrict__ nf)
{
    const float px = 511.0f * (float)col * (1.0f / 255.0f);
    const float py = 511.0f * (float)row * (1.0f / 255.0f);

    const float* K = intrs + view * 9;
    const float a = K[0], b = K[1], c = K[2];
    const float d = K[3], e = K[4], f = K[5];
    const float g = K[6], h = K[7], i9 = K[8];
    const float det = a * (e * i9 - f * h) - b * (d * i9 - f * g) + c * (d * h - e * g);
    const float id = 1.0f / det;
    const float m00 = (e * i9 - f * h) * id, m01 = -(b * i9 - c * h) * id, m02 = (b * f - c * e) * id;
    const float m10 = -(d * i9 - f * g) * id, m11 = (a * i9 - c * g) * id, m12 = -(a * f - c * d) * id;
    const float m20 = (d * h - e * g) * id, m21 = -(a * h - b * g) * id, m22 = (a * e - b * d) * id;

    const float cx = m00 * px + m01 * py + m02;
    const float cy = m10 * px + m11 * py + m12;
    const float cz = m20 * px + m21 * py + m22;
    const float inr = rsqrtf(cx * cx + cy * cy + cz * cz);
    const float ncz = cz * inr;

    const float ncx = cx * inr, ncy = cy * inr;
    const float* M = c2ws + view * 16;
    const float dx = M[0] * ncx + M[1] * ncy + M[2] * ncz;
    const float dy = M[4] * ncx + M[5] * ncy + M[6] * ncz;
    const float dz = M[8] * ncx + M[9] * ncy + M[10] * ncz;
    const float tx = M[3], ty = M[7], tz = M[11];

    const float z0 = nf[view * 2 + 0];
    const float zstep = (nf[view * 2 + 1] - z0) * (1.0f / 63.0f);

    Ray r;
    const float gx0 = (tx + 1.0f) * 63.5f, gxs = dx * 63.5f;
    const float gy0 = (ty + 1.0f) * 63.5f, gys = dy * 63.5f;
    const float gz0 = (tz + 1.0f) * 63.5f, gzs = dz * 63.5f;
    r.ax0 = fmaf(gxs, z0, gx0); r.axs = gxs * zstep;
    r.ay0 = fmaf(gys, z0, gy0); r.ays = gys * zstep;
    r.az0 = fmaf(gzs, z0, gz0); r.azs = gzs * zstep;

    const float bq = tx * dx + ty * dy + tz * dz;
    const float cq = tx * tx + ty * ty + tz * tz;
    const float disc = bq * bq - (cq - 1.0f);
    if (disc >= 0.0f) {
        const float rt = sqrtf(disc);
        const float inv = 1.0f / zstep;
        r.sLo = (-bq - rt - z0) * inv;
        r.sHi = (-bq + rt - z0) * inv;
    } else {
        r.sLo = 3.4e38f;
        r.sHi = 0.0f;
    }

    r.z0 = z0;
    r.zstep = zstep;
    r.ncz = ncz;
    return r;
}

// ---------------- build: z-paired f16 quad table, pre-scaled by log2(e) ----
// F[z][y][x] = uint4; word k = __half2 (corner@z0, corner@z1):
//   w0=(c000,c100) w1=(c001,c101) w2=(c010,c110) w3=(c011,c111)
__global__ __launch_bounds__(BLK) void build_quad_kernel(
    const float* __restrict__ vol, uint4* __restrict__ F)
{
    const int id = blockIdx.x * BLK + threadIdx.x;
    const int x = id & 127;
    const int y = (id >> 7) & 127;
    const int z = id >> 14;
    const int yp = min(y + 1, 127);
    const int zp = min(z + 1, 127);
    const int xb = min(x, 126);
    const int sel = x - xb;      // 0 or 1; x==127 -> both corners = v.y

    const float2 v00 = *reinterpret_cast<const float2*>(vol + (z  * VOLN + y ) * VOLN + xb);
    const float2 v01 = *reinterpret_cast<const float2*>(vol + (z  * VOLN + yp) * VOLN + xb);
    const float2 v10 = *reinterpret_cast<const float2*>(vol + (zp * VOLN + y ) * VOLN + xb);
    const float2 v11 = *reinterpret_cast<const float2*>(vol + (zp * VOLN + yp) * VOLN + xb);

    const float c000 = sel ? v00.y : v00.x, c001 = v00.y;
    const float c010 = sel ? v01.y : v01.x, c011 = v01.y;
    const float c100 = sel ? v10.y : v10.x, c101 = v10.y;
    const float c110 = sel ? v11.y : v11.x, c111 = v11.y;

    const __half2 w0 = __floats2half2_rn(c000 * LOG2E, c100 * LOG2E);
    const __half2 w1 = __floats2half2_rn(c001 * LOG2E, c101 * LOG2E);
    const __half2 w2 = __floats2half2_rn(c010 * LOG2E, c110 * LOG2E);
    const __half2 w3 = __floats2half2_rn(c011 * LOG2E, c111 * LOG2E);
    uint4 o;
    o.x = *reinterpret_cast<const unsigned*>(&w0);
    o.y = *reinterpret_cast<const unsigned*>(&w1);
    o.z = *reinterpret_cast<const unsigned*>(&w2);
    o.w = *reinterpret_cast<const unsigned*>(&w3);
    F[id] = o;
}

// ---------------- raymarch: quad f16, 2-deep software-pipelined batches ----
__global__ __launch_bounds__(BLK) void raymarch_quad_kernel(
    const float* __restrict__ intrs, const float* __restrict__ c2ws,
    const float* __restrict__ nf, const uint4* __restrict__ F,
    float* __restrict__ depth_low, float* __restrict__ partials)
{
    const int wg  = blockIdx.x;
    const int swz = (wg & (NXCD - 1)) * CHUNK + (wg >> 3); // bijective, 768=8*96
    const int view = swz >> 8;
    const int row  = swz & 255;
    const int t    = threadIdx.x;

    const Ray r = ray_setup(view, row, t, intrs, c2ws, nf);

    // closed-form outside-sample count (saves a per-sample add)
    const float ilo = ceilf(fmaxf(r.sLo, 0.0f));
    const float ihi = floorf(fminf(r.sHi, 63.0f));
    const float cnt = 64.0f - fmaxf(0.0f, ihi - ilo + 1.0f);

    float lsum = 0.0f, sacc = 0.0f, d6 = 0.0f, dout = 0.0f;

    float fxs[2][8], fys[2][8], fzs[2][8];
    uint4 q[2][8];

// compute addresses + issue 8 loads into bank BK for samples SB..SB+7
#define ADDR_BATCH(BK, SB)                                                    \
    {                                                                         \
        unsigned offs[8];                                                     \
        _Pragma("unroll")                                                     \
        for (int i = 0; i < 8; ++i) {                                         \
            const float sf = (float)((SB) + i);                               \
            float gx = fmaf(r.axs, sf, r.ax0);                                \
            float gy = fmaf(r.ays, sf, r.ay0);                                \
            float gz = fmaf(r.azs, sf, r.az0);                                \
            gx = fminf(fmaxf(gx, 0.0f), 126.9995f);                           \
            gy = fminf(fmaxf(gy, 0.0f), 126.9995f);                           \
            gz = fminf(fmaxf(gz, 0.0f), 126.9995f);                           \
            const float xbf = floorf(gx);                                     \
            const float ybf = floorf(gy);                                     \
            const float zbf = floorf(gz);                                     \
            fxs[BK][i] = gx - xbf;                                            \
            fys[BK][i] = gy - ybf;                                            \
            fzs[BK][i] = gz - zbf;                                            \
            offs[i] = (unsigned)fmaf(zbf, 16384.0f, fmaf(ybf, 128.0f, xbf));  \
        }                                                                     \
        _Pragma("unroll")                                                     \
        for (int i = 0; i < 8; ++i) q[BK][i] = F[offs[i]];                    \
    }

#define CONSUME_BATCH(BK, SB)                                                 \
    _Pragma("unroll")                                                         \
    for (int i = 0; i < 8; ++i) {                                             \
        const float sf = (float)((SB) + i);                                   \
        union { unsigned u; __half2 h; } a0, a1, b0, b1;                      \
        a0.u = q[BK][i].x; a1.u = q[BK][i].y;                                 \
        b0.u = q[BK][i].z; b1.u = q[BK][i].w;                                 \
        const __half2 fxh = __float2half2_rn(fxs[BK][i]);                     \
        const __half2 fyh = __float2half2_rn(fys[BK][i]);                     \
        const __half2 cx0 = __hfma2(fxh, __hsub2(a1.h, a0.h), a0.h);          \
        const __half2 cx1 = __hfma2(fxh, __hsub2(b1.h, b0.h), b0.h);          \
        const __half2 cy  = __hfma2(fyh, __hsub2(cx1, cx0), cx0);             \
        const float c0 = __low2float(cy);                                     \
        const float c1 = __high2float(cy);                                    \
        const float dens = fmaf(fzs[BK][i], c1 - c0, c0);  /* = log2e*rho */  \
        const float w = exp2f(dens);                       /* = e^rho */      \
        lsum += w;                                                            \
        sacc = fmaf(sf, w, sacc);                                             \
        if ((SB) == 0 && i < 6) d6 += dens;                                   \
        const bool o = (sf < r.sLo) || (sf > r.sHi);                          \
        dout += o ? dens : 0.0f;                                              \
    }

    ADDR_BATCH(0, 0)
    #pragma unroll
    for (int b = 0; b < 8; ++b) {
        if (b < 7) {                       // issue next batch before consuming
            if (b & 1) { ADDR_BATCH(0, (b + 1) * 8) }
            else       { ADDR_BATCH(1, (b + 1) * 8) }
        }
        if (b & 1) { CONSUME_BATCH(1, b * 8) }
        else       { CONSUME_BATCH(0, b * 8) }
    }
#undef ADDR_BATCH
#undef CONSUME_BATCH

    depth_low[view * NPIX + row * WLOW + t] =
        fmaf(r.zstep, sacc / lsum, r.z0) * r.ncz;

    __shared__ float s0[BLK], s1[BLK], s2[BLK];
    s0[t] = d6; s1[t] = dout; s2[t] = cnt;
    __syncthreads();
    for (int off = BLK / 2; off > 0; off >>= 1) {
        if (t < off) {
            s0[t] += s0[t + off];
            s1[t] += s1[t + off];
            s2[t] += s2[t + off];
        }
        __syncthreads();
    }
    if (t == 0) {
        partials[swz * 3 + 0] = s0[0] * INV_LOG2E;   // un-scale linear sums
        partials[swz * 3 + 1] = s1[0] * INV_LOG2E;
        partials[swz * 3 + 2] = s2[0];
    }
}

// ---------------- fallback raymarch: f32 volume direct (tiny ws) ----------
__global__ __launch_bounds__(BLK) void raymarch_f32_kernel(
    const float* __restrict__ intrs, const float* __restrict__ c2ws,
    const float* __restrict__ nf, const float* __restrict__ vol,
    float* __restrict__ depth_low, float* __restrict__ partials)
{
    const int view = blockIdx.x >> 8;
    const int row  = blockIdx.x & 255;
    const int t    = threadIdx.x;

    const Ray r = ray_setup(view, row, t, intrs, c2ws, nf);

    const float ilo = ceilf(fmaxf(r.sLo, 0.0f));
    const float ihi = floorf(fminf(r.sHi, 63.0f));
    const float cnt = 64.0f - fmaxf(0.0f, ihi - ilo + 1.0f);

    float lsum = 0.0f, sacc = 0.0f, d6 = 0.0f, dout = 0.0f;

    #pragma unroll 16
    for (int s = 0; s < NS; ++s) {
        const float sf = (float)s;
        float gx = fmaf(r.axs, sf, r.ax0);
        float gy = fmaf(r.ays, sf, r.ay0);
        float gz = fmaf(r.azs, sf, r.az0);
        gx = fminf(fmaxf(gx, 0.0f), 126.9995f);
        gy = fminf(fmaxf(gy, 0.0f), 126.9995f);
        gz = fminf(fmaxf(gz, 0.0f), 126.9995f);
        const float xbf = floorf(gx);
        const float ybf = floorf(gy);
        const float zbf = floorf(gz);
        const float fx = gx - xbf, fy = gy - ybf, fz = gz - zbf;
        const unsigned off = (unsigned)fmaf(zbf, 16384.0f, fmaf(ybf, 128.0f, xbf));

        const float* p0 = vol + off;
        const float2 v00 = *reinterpret_cast<const float2*>(p0);
        const float2 v01 = *reinterpret_cast<const float2*>(p0 + VOLN);
        const float2 v10 = *reinterpret_cast<const float2*>(p0 + VOLN * VOLN);
        const float2 v11 = *reinterpret_cast<const float2*>(p0 + VOLN * VOLN + VOLN);

        const float c00 = fmaf(fx, v00.y - v00.x, v00.x);
        const float c01 = fmaf(fx, v01.y - v01.x, v01.x);
        const float c10 = fmaf(fx, v10.y - v10.x, v10.x);
        const float c11 = fmaf(fx, v11.y - v11.x, v11.x);
        const float c0 = fmaf(fy, c01 - c00, c00);
        const float c1 = fmaf(fy, c11 - c10, c10);
        const float dens = fmaf(fz, c1 - c0, c0);

        const float w = __expf(dens);
        lsum += w;
        sacc = fmaf(sf, w, sacc);

        if (s < 6) d6 += dens;
        const bool o = (sf < r.sLo) || (sf > r.sHi);
        dout += o ? dens : 0.0f;
    }

    depth_low[view * NPIX + row * WLOW + t] =
        fmaf(r.zstep, sacc / lsum, r.z0) * r.ncz;

    __shared__ float s0[BLK], s1[BLK], s2[BLK];
    s0[t] = d6; s1[t] = dout; s2[t] = cnt;
    __syncthreads();
    for (int off = BLK / 2; off > 0; off >>= 1) {
        if (t < off) {
            s0[t] += s0[t + off];
            s1[t] += s1[t + off];
            s2[t] += s2[t + off];
        }
        __syncthreads();
    }
    if (t == 0) {
        partials[blockIdx.x * 3 + 0] = s0[0];
        partials[blockIdx.x * 3 + 1] = s1[0];
        partials[blockIdx.x * 3 + 2] = s2[0];
    }
}

// ---------------- fused epilogue: upsample (2 px/thread) + occ reduce ----
__global__ __launch_bounds__(BLK) void epilogue_kernel(
    const float* __restrict__ low, const float* __restrict__ partials,
    float* __restrict__ out)
{
    if (blockIdx.x >= UPS2_BLOCKS) {
        const int view = blockIdx.x - UPS2_BLOCKS;
        const int t = threadIdx.x;
        __shared__ float s0[BLK], s1[BLK], s2[BLK];
        const int bi = view * BLOCKS_PER_VIEW + t; // BLOCKS_PER_VIEW == BLK
        s0[t] = partials[bi * 3 + 0];
        s1[t] = partials[bi * 3 + 1];
        s2[t] = partials[bi * 3 + 2];
        __syncthreads();
        for (int off = BLK / 2; off > 0; off >>= 1) {
            if (t < off) {
                s0[t] += s0[t + off];
                s1[t] += s1[t + off];
                s2[t] += s2[t + off];
            }
            __syncthreads();
        }
        if (t == 0) {
            out[NVIEW * IMGH * IMGW + view] =
                s0[0] * (1.0f / (float)(NPIX * 6)) + s1[0] / (s2[0] + 1e-10f);
        }
        return;
    }

    const int idx2 = blockIdx.x * BLK + threadIdx.x;
    const int view = idx2 / (IMGH * IMGW / 2);
    const int rem  = idx2 - view * (IMGH * IMGW / 2);
    const int rr = rem >> 8;
    const int cp = rem & 255;
    const int cc0 = cp * 2;

    const float sy = (float)rr * 0.5f - 0.25f;
    const float y0f = floorf(sy);
    const float wy = sy - y0f;
    const int y0 = (int)y0f;
    const int y0c = max(y0, 0), y1c = min(y0 + 1, HLOW - 1);
    const float* src = low + view * NPIX;
    const float* r0 = src + y0c * WLOW;
    const float* r1 = src + y1c * WLOW;

    float2 res;
    {
        const float sx = (float)cc0 * 0.5f - 0.25f;
        const float x0f = floorf(sx);
        const float wx = sx - x0f;
        const int x0 = (int)x0f;
        const int x0c = max(x0, 0), x1c = min(x0 + 1, WLOW - 1);
        const float top = r0[x0c] * (1.0f - wx) + r0[x1c] * wx;
        const float bot = r1[x0c] * (1.0f - wx) + r1[x1c] * wx;
        res.x = top * (1.0f - wy) + bot * wy;
    }
    {
        const int cc1 = cc0 + 1;
        const float sx = (float)cc1 * 0.5f - 0.25f;
        const float x0f = floorf(sx);
        const float wx = sx - x0f;
        const int x0 = (int)x0f;
        const int x0c = max(x0, 0), x1c = min(x0 + 1, WLOW - 1);
        const float top = r0[x0c] * (1.0f - wx) + r0[x1c] * wx;
        const float bot = r1[x0c] * (1.0f - wx) + r1[x1c] * wx;
        res.y = top * (1.0f - wy) + bot * wy;
    }
    *reinterpret_cast<float2*>(out + view * (IMGH * IMGW) + rr * IMGW + cc0) = res;
}

extern "C" void kernel_launch(void* const* d_in, const int* in_sizes, int n_in,
                              void* d_out, int out_size, void* d_ws, size_t ws_size,
                              hipStream_t stream) {
    // input order: imgs, intrs, c2ws, near_fars, density_volume, stage_idx
    const float* intrs = (const float*)d_in[1];
    const float* c2ws  = (const float*)d_in[2];
    const float* nf    = (const float*)d_in[3];
    const float* vol   = (const float*)d_in[4];
    float* out = (float*)d_out;

    const size_t quad_bytes  = (size_t)NVOX * 16;
    const size_t depth_bytes = (size_t)NVIEW * NPIX * 4;
    const size_t part_bytes  = (size_t)NVIEW * BLOCKS_PER_VIEW * 3 * 4;
    char* ws = (char*)d_ws;

    float* depth_low;
    float* partials;

    if (ws_size >= quad_bytes + depth_bytes + part_bytes) {
        uint4* F = (uint4*)ws;
        depth_low = (float*)(ws + quad_bytes);
        partials  = depth_low + NVIEW * NPIX;
        build_quad_kernel<<<NVOX / BLK, BLK, 0, stream>>>(vol, F);
        raymarch_quad_kernel<<<MARCH_BLOCKS, BLK, 0, stream>>>(
            intrs, c2ws, nf, F, depth_low, partials);
    } else {
        depth_low = (float*)ws;
        partials  = depth_low + NVIEW * NPIX;
        raymarch_f32_kernel<<<MARCH_BLOCKS, BLK, 0, stream>>>(
            intrs, c2ws, nf, vol, depth_low, partials);
    }

    epilogue_kernel<<<UPS2_BLOCKS + NVIEW, BLK, 0, stream>>>(depth_low, partials, out);
}

// Round 10
// 37.328 us; speedup vs baseline: 1.3815x; 1.0029x over previous
//
#include <hip/hip_runtime.h>
#include <hip/hip_fp16.h>
#include <math.h>

#define NVIEW 3
#define HLOW 256
#define WLOW 256
#define NPIX (HLOW * WLOW)
#define NS 64
#define VOLN 128
#define IMGH 512
#define IMGW 512
#define BLK 256
#define BLOCKS_PER_VIEW (NPIX / BLK)   // 256 (one block per low-res row)
#define NVOX (VOLN * VOLN * VOLN)      // 2097152
#define UPS2_BLOCKS ((NVIEW * IMGH * IMGW / 2) / BLK) // 1536 (2 px per thread)
#define NXCD 8
#define MARCH_BLOCKS (NVIEW * BLOCKS_PER_VIEW)        // 768
#define CHUNK (MARCH_BLOCKS / NXCD)                   // 96

#define LOG2E     1.4426950408889634f
#define INV_LOG2E 0.6931471805599453f

typedef _Float16 h2 __attribute__((ext_vector_type(2)));

// ---------------- per-ray setup: everything affine in SAMPLE INDEX s ------
struct Ray {
    float ax0, axs, ay0, ays, az0, azs;  // grid coords affine in s
    float sLo, sHi;                      // outside-sphere bounds in s-space
    float z0, zstep, ncz;
};

__device__ __forceinline__ Ray ray_setup(
    int view, int row, int col,
    const float* __restrict__ intrs, const float* __restrict__ c2ws,
    const float* __restrict__ nf)
{
    const float px = 511.0f * (float)col * (1.0f / 255.0f);
    const float py = 511.0f * (float)row * (1.0f / 255.0f);

    const float* K = intrs + view * 9;
    const float a = K[0], b = K[1], c = K[2];
    const float d = K[3], e = K[4], f = K[5];
    const float g = K[6], h = K[7], i9 = K[8];
    const float det = a * (e * i9 - f * h) - b * (d * i9 - f * g) + c * (d * h - e * g);
    const float id = 1.0f / det;
    const float m00 = (e * i9 - f * h) * id, m01 = -(b * i9 - c * h) * id, m02 = (b * f - c * e) * id;
    const float m10 = -(d * i9 - f * g) * id, m11 = (a * i9 - c * g) * id, m12 = -(a * f - c * d) * id;
    const float m20 = (d * h - e * g) * id, m21 = -(a * h - b * g) * id, m22 = (a * e - b * d) * id;

    const float cx = m00 * px + m01 * py + m02;
    const float cy = m10 * px + m11 * py + m12;
    const float cz = m20 * px + m21 * py + m22;
    const float inr = rsqrtf(cx * cx + cy * cy + cz * cz);
    const float ncz = cz * inr;

    const float ncx = cx * inr, ncy = cy * inr;
    const float* M = c2ws + view * 16;
    const float dx = M[0] * ncx + M[1] * ncy + M[2] * ncz;
    const float dy = M[4] * ncx + M[5] * ncy + M[6] * ncz;
    const float dz = M[8] * ncx + M[9] * ncy + M[10] * ncz;
    const float tx = M[3], ty = M[7], tz = M[11];

    const float z0 = nf[view * 2 + 0];
    const float zstep = (nf[view * 2 + 1] - z0) * (1.0f / 63.0f);

    Ray r;
    const float gx0 = (tx + 1.0f) * 63.5f, gxs = dx * 63.5f;
    const float gy0 = (ty + 1.0f) * 63.5f, gys = dy * 63.5f;
    const float gz0 = (tz + 1.0f) * 63.5f, gzs = dz * 63.5f;
    r.ax0 = fmaf(gxs, z0, gx0); r.axs = gxs * zstep;
    r.ay0 = fmaf(gys, z0, gy0); r.ays = gys * zstep;
    r.az0 = fmaf(gzs, z0, gz0); r.azs = gzs * zstep;

    const float bq = tx * dx + ty * dy + tz * dz;
    const float cq = tx * tx + ty * ty + tz * tz;
    const float disc = bq * bq - (cq - 1.0f);
    if (disc >= 0.0f) {
        const float rt = sqrtf(disc);
        const float inv = 1.0f / zstep;
        r.sLo = (-bq - rt - z0) * inv;
        r.sHi = (-bq + rt - z0) * inv;
    } else {
        r.sLo = 3.4e38f;
        r.sHi = 0.0f;
    }

    r.z0 = z0;
    r.zstep = zstep;
    r.ncz = ncz;
    return r;
}

// ---------------- build: z-paired f16 quad table, pre-scaled by log2(e) ----
// F[z][y][x] = uint4; word k = __half2 (corner@z0, corner@z1):
//   w0=(c000,c100) w1=(c001,c101) w2=(c010,c110) w3=(c011,c111)
__global__ __launch_bounds__(BLK) void build_quad_kernel(
    const float* __restrict__ vol, uint4* __restrict__ F)
{
    const int id = blockIdx.x * BLK + threadIdx.x;
    const int x = id & 127;
    const int y = (id >> 7) & 127;
    const int z = id >> 14;
    const int yp = min(y + 1, 127);
    const int zp = min(z + 1, 127);
    const int xb = min(x, 126);
    const int sel = x - xb;      // 0 or 1; x==127 -> both corners = v.y

    const float2 v00 = *reinterpret_cast<const float2*>(vol + (z  * VOLN + y ) * VOLN + xb);
    const float2 v01 = *reinterpret_cast<const float2*>(vol + (z  * VOLN + yp) * VOLN + xb);
    const float2 v10 = *reinterpret_cast<const float2*>(vol + (zp * VOLN + y ) * VOLN + xb);
    const float2 v11 = *reinterpret_cast<const float2*>(vol + (zp * VOLN + yp) * VOLN + xb);

    const float c000 = sel ? v00.y : v00.x, c001 = v00.y;
    const float c010 = sel ? v01.y : v01.x, c011 = v01.y;
    const float c100 = sel ? v10.y : v10.x, c101 = v10.y;
    const float c110 = sel ? v11.y : v11.x, c111 = v11.y;

    const __half2 w0 = __floats2half2_rn(c000 * LOG2E, c100 * LOG2E);
    const __half2 w1 = __floats2half2_rn(c001 * LOG2E, c101 * LOG2E);
    const __half2 w2 = __floats2half2_rn(c010 * LOG2E, c110 * LOG2E);
    const __half2 w3 = __floats2half2_rn(c011 * LOG2E, c111 * LOG2E);
    uint4 o;
    o.x = *reinterpret_cast<const unsigned*>(&w0);
    o.y = *reinterpret_cast<const unsigned*>(&w1);
    o.z = *reinterpret_cast<const unsigned*>(&w2);
    o.w = *reinterpret_cast<const unsigned*>(&w3);
    F[id] = o;
}

// ---------------- raymarch: quad f16, 2-deep pipeline, dot2 z-lerp --------
__global__ __launch_bounds__(BLK) void raymarch_quad_kernel(
    const float* __restrict__ intrs, const float* __restrict__ c2ws,
    const float* __restrict__ nf, const uint4* __restrict__ F,
    float* __restrict__ depth_low, float* __restrict__ partials)
{
    const int wg  = blockIdx.x;
    const int swz = (wg & (NXCD - 1)) * CHUNK + (wg >> 3); // bijective, 768=8*96
    const int view = swz >> 8;
    const int row  = swz & 255;
    const int t    = threadIdx.x;

    const Ray r = ray_setup(view, row, t, intrs, c2ws, nf);

    // closed-form outside-sample count
    const float ilo = ceilf(fmaxf(r.sLo, 0.0f));
    const float ihi = floorf(fminf(r.sHi, 63.0f));
    const float cnt = 64.0f - fmaxf(0.0f, ihi - ilo + 1.0f);

    float lsum = 0.0f, sacc = 0.0f, d6 = 0.0f, dout = 0.0f;

    h2 fx2[2][8], fy2[2][8], fw2[2][8];   // fw2 = (1-fz, fz)
    uint4 q[2][8];

// compute addresses + frac half-vectors + issue 8 loads into bank BK
#define ADDR_BATCH(BK, SB)                                                    \
    {                                                                         \
        unsigned offs[8];                                                     \
        _Pragma("unroll")                                                     \
        for (int i = 0; i < 8; ++i) {                                         \
            const float sf = (float)((SB) + i);                               \
            float gx = fmaf(r.axs, sf, r.ax0);                                \
            float gy = fmaf(r.ays, sf, r.ay0);                                \
            float gz = fmaf(r.azs, sf, r.az0);                                \
            gx = fminf(fmaxf(gx, 0.0f), 126.9995f);                           \
            gy = fminf(fmaxf(gy, 0.0f), 126.9995f);                           \
            gz = fminf(fmaxf(gz, 0.0f), 126.9995f);                           \
            const float xbf = floorf(gx);                                     \
            const float ybf = floorf(gy);                                     \
            const float zbf = floorf(gz);                                     \
            const float fx = gx - xbf;                                        \
            const float fy = gy - ybf;                                        \
            const float fz = gz - zbf;                                        \
            fx2[BK][i] = (h2){(_Float16)fx, (_Float16)fx};                    \
            fy2[BK][i] = (h2){(_Float16)fy, (_Float16)fy};                    \
            fw2[BK][i] = (h2){(_Float16)(1.0f - fz), (_Float16)fz};           \
            offs[i] = (unsigned)fmaf(zbf, 16384.0f, fmaf(ybf, 128.0f, xbf));  \
        }                                                                     \
        _Pragma("unroll")                                                     \
        for (int i = 0; i < 8; ++i) q[BK][i] = F[offs[i]];                    \
    }

#define CONSUME_BATCH(BK, SB)                                                 \
    _Pragma("unroll")                                                         \
    for (int i = 0; i < 8; ++i) {                                             \
        const float sf = (float)((SB) + i);                                   \
        const h2 a0 = __builtin_bit_cast(h2, q[BK][i].x);                     \
        const h2 a1 = __builtin_bit_cast(h2, q[BK][i].y);                     \
        const h2 b0 = __builtin_bit_cast(h2, q[BK][i].z);                     \
        const h2 b1 = __builtin_bit_cast(h2, q[BK][i].w);                     \
        const h2 cx0 = fx2[BK][i] * (a1 - a0) + a0;   /* v_pk ops */          \
        const h2 cx1 = fx2[BK][i] * (b1 - b0) + b0;                           \
        const h2 cyv = fy2[BK][i] * (cx1 - cx0) + cx0;                        \
        const float dens =                                                    \
            __builtin_amdgcn_fdot2(cyv, fw2[BK][i], 0.0f, false);             \
        const float w = exp2f(dens);                  /* = e^rho */           \
        lsum += w;                                                            \
        sacc = fmaf(sf, w, sacc);                                             \
        if ((SB) == 0 && i < 6) d6 += dens;                                   \
        const bool o = (sf < r.sLo) || (sf > r.sHi);                          \
        dout += o ? dens : 0.0f;                                              \
    }

    ADDR_BATCH(0, 0)
    #pragma unroll
    for (int b = 0; b < 8; ++b) {
        if (b < 7) {                       // issue next batch before consuming
            if (b & 1) { ADDR_BATCH(0, (b + 1) * 8) }
            else       { ADDR_BATCH(1, (b + 1) * 8) }
        }
        if (b & 1) { CONSUME_BATCH(1, b * 8) }
        else       { CONSUME_BATCH(0, b * 8) }
    }
#undef ADDR_BATCH
#undef CONSUME_BATCH

    depth_low[view * NPIX + row * WLOW + t] =
        fmaf(r.zstep, sacc / lsum, r.z0) * r.ncz;

    __shared__ float s0[BLK], s1[BLK], s2[BLK];
    s0[t] = d6; s1[t] = dout; s2[t] = cnt;
    __syncthreads();
    for (int off = BLK / 2; off > 0; off >>= 1) {
        if (t < off) {
            s0[t] += s0[t + off];
            s1[t] += s1[t + off];
            s2[t] += s2[t + off];
        }
        __syncthreads();
    }
    if (t == 0) {
        partials[swz * 3 + 0] = s0[0] * INV_LOG2E;   // un-scale linear sums
        partials[swz * 3 + 1] = s1[0] * INV_LOG2E;
        partials[swz * 3 + 2] = s2[0];
    }
}

// ---------------- fallback raymarch: f32 volume direct (tiny ws) ----------
__global__ __launch_bounds__(BLK) void raymarch_f32_kernel(
    const float* __restrict__ intrs, const float* __restrict__ c2ws,
    const float* __restrict__ nf, const float* __restrict__ vol,
    float* __restrict__ depth_low, float* __restrict__ partials)
{
    const int view = blockIdx.x >> 8;
    const int row  = blockIdx.x & 255;
    const int t    = threadIdx.x;

    const Ray r = ray_setup(view, row, t, intrs, c2ws, nf);

    const float ilo = ceilf(fmaxf(r.sLo, 0.0f));
    const float ihi = floorf(fminf(r.sHi, 63.0f));
    const float cnt = 64.0f - fmaxf(0.0f, ihi - ilo + 1.0f);

    float lsum = 0.0f, sacc = 0.0f, d6 = 0.0f, dout = 0.0f;

    #pragma unroll 16
    for (int s = 0; s < NS; ++s) {
        const float sf = (float)s;
        float gx = fmaf(r.axs, sf, r.ax0);
        float gy = fmaf(r.ays, sf, r.ay0);
        float gz = fmaf(r.azs, sf, r.az0);
        gx = fminf(fmaxf(gx, 0.0f), 126.9995f);
        gy = fminf(fmaxf(gy, 0.0f), 126.9995f);
        gz = fminf(fmaxf(gz, 0.0f), 126.9995f);
        const float xbf = floorf(gx);
        const float ybf = floorf(gy);
        const float zbf = floorf(gz);
        const float fx = gx - xbf, fy = gy - ybf, fz = gz - zbf;
        const unsigned off = (unsigned)fmaf(zbf, 16384.0f, fmaf(ybf, 128.0f, xbf));

        const float* p0 = vol + off;
        const float2 v00 = *reinterpret_cast<const float2*>(p0);
        const float2 v01 = *reinterpret_cast<const float2*>(p0 + VOLN);
        const float2 v10 = *reinterpret_cast<const float2*>(p0 + VOLN * VOLN);
        const float2 v11 = *reinterpret_cast<const float2*>(p0 + VOLN * VOLN + VOLN);

        const float c00 = fmaf(fx, v00.y - v00.x, v00.x);
        const float c01 = fmaf(fx, v01.y - v01.x, v01.x);
        const float c10 = fmaf(fx, v10.y - v10.x, v10.x);
        const float c11 = fmaf(fx, v11.y - v11.x, v11.x);
        const float c0 = fmaf(fy, c01 - c00, c00);
        const float c1 = fmaf(fy, c11 - c10, c10);
        const float dens = fmaf(fz, c1 - c0, c0);

        const float w = __expf(dens);
        lsum += w;
        sacc = fmaf(sf, w, sacc);

        if (s < 6) d6 += dens;
        const bool o = (sf < r.sLo) || (sf > r.sHi);
        dout += o ? dens : 0.0f;
    }

    depth_low[view * NPIX + row * WLOW + t] =
        fmaf(r.zstep, sacc / lsum, r.z0) * r.ncz;

    __shared__ float s0[BLK], s1[BLK], s2[BLK];
    s0[t] = d6; s1[t] = dout; s2[t] = cnt;
    __syncthreads();
    for (int off = BLK / 2; off > 0; off >>= 1) {
        if (t < off) {
            s0[t] += s0[t + off];
            s1[t] += s1[t + off];
            s2[t] += s2[t + off];
        }
        __syncthreads();
    }
    if (t == 0) {
        partials[blockIdx.x * 3 + 0] = s0[0];
        partials[blockIdx.x * 3 + 1] = s1[0];
        partials[blockIdx.x * 3 + 2] = s2[0];
    }
}

// ---------------- fused epilogue: upsample (2 px/thread) + occ reduce ----
__global__ __launch_bounds__(BLK) void epilogue_kernel(
    const float* __restrict__ low, const float* __restrict__ partials,
    float* __restrict__ out)
{
    if (blockIdx.x >= UPS2_BLOCKS) {
        const int view = blockIdx.x - UPS2_BLOCKS;
        const int t = threadIdx.x;
        __shared__ float s0[BLK], s1[BLK], s2[BLK];
        const int bi = view * BLOCKS_PER_VIEW + t; // BLOCKS_PER_VIEW == BLK
        s0[t] = partials[bi * 3 + 0];
        s1[t] = partials[bi * 3 + 1];
        s2[t] = partials[bi * 3 + 2];
        __syncthreads();
        for (int off = BLK / 2; off > 0; off >>= 1) {
            if (t < off) {
                s0[t] += s0[t + off];
                s1[t] += s1[t + off];
                s2[t] += s2[t + off];
            }
            __syncthreads();
        }
        if (t == 0) {
            out[NVIEW * IMGH * IMGW + view] =
                s0[0] * (1.0f / (float)(NPIX * 6)) + s1[0] / (s2[0] + 1e-10f);
        }
        return;
    }

    const int idx2 = blockIdx.x * BLK + threadIdx.x;
    const int view = idx2 / (IMGH * IMGW / 2);
    const int rem  = idx2 - view * (IMGH * IMGW / 2);
    const int rr = rem >> 8;
    const int cp = rem & 255;
    const int cc0 = cp * 2;

    const float sy = (float)rr * 0.5f - 0.25f;
    const float y0f = floorf(sy);
    const float wy = sy - y0f;
    const int y0 = (int)y0f;
    const int y0c = max(y0, 0), y1c = min(y0 + 1, HLOW - 1);
    const float* src = low + view * NPIX;
    const float* r0 = src + y0c * WLOW;
    const float* r1 = src + y1c * WLOW;

    float2 res;
    {
        const float sx = (float)cc0 * 0.5f - 0.25f;
        const float x0f = floorf(sx);
        const float wx = sx - x0f;
        const int x0 = (int)x0f;
        const int x0c = max(x0, 0), x1c = min(x0 + 1, WLOW - 1);
        const float top = r0[x0c] * (1.0f - wx) + r0[x1c] * wx;
        const float bot = r1[x0c] * (1.0f - wx) + r1[x1c] * wx;
        res.x = top * (1.0f - wy) + bot * wy;
    }
    {
        const int cc1 = cc0 + 1;
        const float sx = (float)cc1 * 0.5f - 0.25f;
        const float x0f = floorf(sx);
        const float wx = sx - x0f;
        const int x0 = (int)x0f;
        const int x0c = max(x0, 0), x1c = min(x0 + 1, WLOW - 1);
        const float top = r0[x0c] * (1.0f - wx) + r0[x1c] * wx;
        const float bot = r1[x0c] * (1.0f - wx) + r1[x1c] * wx;
        res.y = top * (1.0f - wy) + bot * wy;
    }
    *reinterpret_cast<float2*>(out + view * (IMGH * IMGW) + rr * IMGW + cc0) = res;
}

extern "C" void kernel_launch(void* const* d_in, const int* in_sizes, int n_in,
                              void* d_out, int out_size, void* d_ws, size_t ws_size,
                              hipStream_t stream) {
    // input order: imgs, intrs, c2ws, near_fars, density_volume, stage_idx
    const float* intrs = (const float*)d_in[1];
    const float* c2ws  = (const float*)d_in[2];
    const float* nf    = (const float*)d_in[3];
    const float* vol   = (const float*)d_in[4];
    float* out = (float*)d_out;

    const size_t quad_bytes  = (size_t)NVOX * 16;
    const size_t depth_bytes = (size_t)NVIEW * NPIX * 4;
    const size_t part_bytes  = (size_t)NVIEW * BLOCKS_PER_VIEW * 3 * 4;
    char* ws = (char*)d_ws;

    float* depth_low;
    float* partials;

    if (ws_size >= quad_bytes + depth_bytes + part_bytes) {
        uint4* F = (uint4*)ws;
        depth_low = (float*)(ws + quad_bytes);
        partials  = depth_low + NVIEW * NPIX;
        build_quad_kernel<<<NVOX / BLK, BLK, 0, stream>>>(vol, F);
        raymarch_quad_kernel<<<MARCH_BLOCKS, BLK, 0, stream>>>(
            intrs, c2ws, nf, F, depth_low, partials);
    } else {
        depth_low = (float*)ws;
        partials  = depth_low + NVIEW * NPIX;
        raymarch_f32_kernel<<<MARCH_BLOCKS, BLK, 0, stream>>>(
            intrs, c2ws, nf, vol, depth_low, partials);
    }

    epilogue_kernel<<<UPS2_BLOCKS + NVIEW, BLK, 0, stream>>>(depth_low, partials, out);
}

// Round 11
// 34.647 us; speedup vs baseline: 1.4884x; 1.0774x over previous
//
#include <hip/hip_runtime.h>
#include <hip/hip_fp16.h>
#include <math.h>

#define NVIEW 3
#define HLOW 256
#define WLOW 256
#define NPIX (HLOW * WLOW)
#define NS 64
#define VOLN 128
#define IMGH 512
#define IMGW 512
#define BLK 256
#define BLOCKS_PER_VIEW (NPIX / BLK)   // 256 (one block per low-res row)
#define NVOX (VOLN * VOLN * VOLN)      // 2097152
#define UPS2_BLOCKS ((NVIEW * IMGH * IMGW / 2) / BLK) // 1536 (2 px per thread)
#define NXCD 8
#define MARCH_BLOCKS (NVIEW * BLOCKS_PER_VIEW)        // 768
#define CHUNK (MARCH_BLOCKS / NXCD)                   // 96

#define LOG2E     1.4426950408889634f
#define INV_LOG2E 0.6931471805599453f

typedef _Float16 h2 __attribute__((ext_vector_type(2)));

// ---------------- per-ray setup: everything affine in SAMPLE INDEX s ------
struct Ray {
    float ax0, axs, ay0, ays, az0, azs;  // grid coords affine in s
    float sLo, sHi;                      // outside-sphere bounds in s-space
    float z0, zstep, ncz;
};

__device__ __forceinline__ Ray ray_setup(
    int view, int row, int col,
    const float* __restrict__ intrs, const float* __restrict__ c2ws,
    const float* __restrict__ nf)
{
    const float px = 511.0f * (float)col * (1.0f / 255.0f);
    const float py = 511.0f * (float)row * (1.0f / 255.0f);

    const float* K = intrs + view * 9;
    const float a = K[0], b = K[1], c = K[2];
    const float d = K[3], e = K[4], f = K[5];
    const float g = K[6], h = K[7], i9 = K[8];
    const float det = a * (e * i9 - f * h) - b * (d * i9 - f * g) + c * (d * h - e * g);
    const float id = 1.0f / det;
    const float m00 = (e * i9 - f * h) * id, m01 = -(b * i9 - c * h) * id, m02 = (b * f - c * e) * id;
    const float m10 = -(d * i9 - f * g) * id, m11 = (a * i9 - c * g) * id, m12 = -(a * f - c * d) * id;
    const float m20 = (d * h - e * g) * id, m21 = -(a * h - b * g) * id, m22 = (a * e - b * d) * id;

    const float cx = m00 * px + m01 * py + m02;
    const float cy = m10 * px + m11 * py + m12;
    const float cz = m20 * px + m21 * py + m22;
    const float inr = rsqrtf(cx * cx + cy * cy + cz * cz);
    const float ncz = cz * inr;

    const float ncx = cx * inr, ncy = cy * inr;
    const float* M = c2ws + view * 16;
    const float dx = M[0] * ncx + M[1] * ncy + M[2] * ncz;
    const float dy = M[4] * ncx + M[5] * ncy + M[6] * ncz;
    const float dz = M[8] * ncx + M[9] * ncy + M[10] * ncz;
    const float tx = M[3], ty = M[7], tz = M[11];

    const float z0 = nf[view * 2 + 0];
    const float zstep = (nf[view * 2 + 1] - z0) * (1.0f / 63.0f);

    Ray r;
    const float gx0 = (tx + 1.0f) * 63.5f, gxs = dx * 63.5f;
    const float gy0 = (ty + 1.0f) * 63.5f, gys = dy * 63.5f;
    const float gz0 = (tz + 1.0f) * 63.5f, gzs = dz * 63.5f;
    r.ax0 = fmaf(gxs, z0, gx0); r.axs = gxs * zstep;
    r.ay0 = fmaf(gys, z0, gy0); r.ays = gys * zstep;
    r.az0 = fmaf(gzs, z0, gz0); r.azs = gzs * zstep;

    const float bq = tx * dx + ty * dy + tz * dz;
    const float cq = tx * tx + ty * ty + tz * tz;
    const float disc = bq * bq - (cq - 1.0f);
    if (disc >= 0.0f) {
        const float rt = sqrtf(disc);
        const float inv = 1.0f / zstep;
        r.sLo = (-bq - rt - z0) * inv;
        r.sHi = (-bq + rt - z0) * inv;
    } else {
        r.sLo = 3.4e38f;
        r.sHi = 0.0f;
    }

    r.z0 = z0;
    r.zstep = zstep;
    r.ncz = ncz;
    return r;
}

// ---------------- build: 8B/cell packed f16 table, pre-scaled by log2(e) --
// P[z][y][x] = uint2:
//   word0 = half2( v[z ][y][x], v[z ][y+1][x] )  (y-pair at z)
//   word1 = half2( v[z+1][y][x], v[z+1][y+1][x] ) (y-pair at z+1)
// The march reads cells x and x+1 with ONE 16B (8B-aligned) load.
__global__ __launch_bounds__(BLK) void build_pack8_kernel(
    const float* __restrict__ vol, uint2* __restrict__ P)
{
    const int id = blockIdx.x * BLK + threadIdx.x;
    const int x = id & 127;
    const int y = (id >> 7) & 127;
    const int z = id >> 14;
    const int yp = min(y + 1, 127);
    const int zp = min(z + 1, 127);

    const float v00 = vol[(z  * VOLN + y ) * VOLN + x];
    const float v01 = vol[(z  * VOLN + yp) * VOLN + x];
    const float v10 = vol[(zp * VOLN + y ) * VOLN + x];
    const float v11 = vol[(zp * VOLN + yp) * VOLN + x];

    const __half2 w0 = __floats2half2_rn(v00 * LOG2E, v01 * LOG2E);
    const __half2 w1 = __floats2half2_rn(v10 * LOG2E, v11 * LOG2E);
    uint2 o;
    o.x = *reinterpret_cast<const unsigned*>(&w0);
    o.y = *reinterpret_cast<const unsigned*>(&w1);
    P[id] = o;
}

// ---------------- raymarch: pack8, 2-deep pipeline, dot2 y-lerp -----------
__global__ __launch_bounds__(BLK) void raymarch_pack8_kernel(
    const float* __restrict__ intrs, const float* __restrict__ c2ws,
    const float* __restrict__ nf, const char* __restrict__ Fb,
    float* __restrict__ depth_low, float* __restrict__ partials)
{
    const int wg  = blockIdx.x;
    const int swz = (wg & (NXCD - 1)) * CHUNK + (wg >> 3); // bijective, 768=8*96
    const int view = swz >> 8;
    const int row  = swz & 255;
    const int t    = threadIdx.x;

    const Ray r = ray_setup(view, row, t, intrs, c2ws, nf);

    // closed-form outside-sample count
    const float ilo = ceilf(fmaxf(r.sLo, 0.0f));
    const float ihi = floorf(fminf(r.sHi, 63.0f));
    const float cnt = 64.0f - fmaxf(0.0f, ihi - ilo + 1.0f);

    float lsum = 0.0f, sacc = 0.0f, d6 = 0.0f, dout = 0.0f;

    h2 fx2[2][8], fyw[2][8];              // fyw = (1-fy, fy)
    float fzs[2][8];
    uint4 q[2][8];

// compute addresses + frac vectors + issue 8 (16B, 8B-aligned) loads
#define ADDR_BATCH(BK, SB)                                                    \
    {                                                                         \
        unsigned offs[8];                                                     \
        _Pragma("unroll")                                                     \
        for (int i = 0; i < 8; ++i) {                                         \
            const float sf = (float)((SB) + i);                               \
            float gx = fmaf(r.axs, sf, r.ax0);                                \
            float gy = fmaf(r.ays, sf, r.ay0);                                \
            float gz = fmaf(r.azs, sf, r.az0);                                \
            gx = fminf(fmaxf(gx, 0.0f), 126.9995f);                           \
            gy = fminf(fmaxf(gy, 0.0f), 126.9995f);                           \
            gz = fminf(fmaxf(gz, 0.0f), 126.9995f);                           \
            const float xbf = floorf(gx);                                     \
            const float ybf = floorf(gy);                                     \
            const float zbf = floorf(gz);                                     \
            const float fx = gx - xbf;                                        \
            const float fy = gy - ybf;                                        \
            fzs[BK][i] = gz - zbf;                                            \
            fx2[BK][i] = (h2){(_Float16)fx, (_Float16)fx};                    \
            fyw[BK][i] = (h2){(_Float16)(1.0f - fy), (_Float16)fy};           \
            offs[i] = (unsigned)fmaf(zbf, 16384.0f, fmaf(ybf, 128.0f, xbf));  \
        }                                                                     \
        _Pragma("unroll")                                                     \
        for (int i = 0; i < 8; ++i)                                           \
            q[BK][i] = *reinterpret_cast<const uint4*>(Fb + (size_t)offs[i] * 8); \
    }

// q = [ypair(x,z0), ypair(x,z1), ypair(x+1,z0), ypair(x+1,z1)]
#define CONSUME_BATCH(BK, SB)                                                 \
    _Pragma("unroll")                                                         \
    for (int i = 0; i < 8; ++i) {                                             \
        const float sf = (float)((SB) + i);                                   \
        const h2 w0 = __builtin_bit_cast(h2, q[BK][i].x);                     \
        const h2 w1 = __builtin_bit_cast(h2, q[BK][i].y);                     \
        const h2 w2 = __builtin_bit_cast(h2, q[BK][i].z);                     \
        const h2 w3 = __builtin_bit_cast(h2, q[BK][i].w);                     \
        const h2 cx0 = fx2[BK][i] * (w2 - w0) + w0;   /* x-lerp @ z0 */       \
        const h2 cx1 = fx2[BK][i] * (w3 - w1) + w1;   /* x-lerp @ z1 */       \
        const float c0 = __builtin_amdgcn_fdot2(cx0, fyw[BK][i], 0.0f, false);\
        const float c1 = __builtin_amdgcn_fdot2(cx1, fyw[BK][i], 0.0f, false);\
        const float dens = fmaf(fzs[BK][i], c1 - c0, c0); /* log2e*rho */     \
        const float w = exp2f(dens);                      /* = e^rho */       \
        lsum += w;                                                            \
        sacc = fmaf(sf, w, sacc);                                             \
        if ((SB) == 0 && i < 6) d6 += dens;                                   \
        const bool o = (sf < r.sLo) || (sf > r.sHi);                          \
        dout += o ? dens : 0.0f;                                              \
    }

    ADDR_BATCH(0, 0)
    #pragma unroll
    for (int b = 0; b < 8; ++b) {
        if (b < 7) {                       // issue next batch before consuming
            if (b & 1) { ADDR_BATCH(0, (b + 1) * 8) }
            else       { ADDR_BATCH(1, (b + 1) * 8) }
        }
        if (b & 1) { CONSUME_BATCH(1, b * 8) }
        else       { CONSUME_BATCH(0, b * 8) }
    }
#undef ADDR_BATCH
#undef CONSUME_BATCH

    depth_low[view * NPIX + row * WLOW + t] =
        fmaf(r.zstep, sacc / lsum, r.z0) * r.ncz;

    __shared__ float s0[BLK], s1[BLK], s2[BLK];
    s0[t] = d6; s1[t] = dout; s2[t] = cnt;
    __syncthreads();
    for (int off = BLK / 2; off > 0; off >>= 1) {
        if (t < off) {
            s0[t] += s0[t + off];
            s1[t] += s1[t + off];
            s2[t] += s2[t + off];
        }
        __syncthreads();
    }
    if (t == 0) {
        partials[swz * 3 + 0] = s0[0] * INV_LOG2E;   // un-scale linear sums
        partials[swz * 3 + 1] = s1[0] * INV_LOG2E;
        partials[swz * 3 + 2] = s2[0];
    }
}

// ---------------- fallback raymarch: f32 volume direct (tiny ws) ----------
__global__ __launch_bounds__(BLK) void raymarch_f32_kernel(
    const float* __restrict__ intrs, const float* __restrict__ c2ws,
    const float* __restrict__ nf, const float* __restrict__ vol,
    float* __restrict__ depth_low, float* __restrict__ partials)
{
    const int view = blockIdx.x >> 8;
    const int row  = blockIdx.x & 255;
    const int t    = threadIdx.x;

    const Ray r = ray_setup(view, row, t, intrs, c2ws, nf);

    const float ilo = ceilf(fmaxf(r.sLo, 0.0f));
    const float ihi = floorf(fminf(r.sHi, 63.0f));
    const float cnt = 64.0f - fmaxf(0.0f, ihi - ilo + 1.0f);

    float lsum = 0.0f, sacc = 0.0f, d6 = 0.0f, dout = 0.0f;

    #pragma unroll 16
    for (int s = 0; s < NS; ++s) {
        const float sf = (float)s;
        float gx = fmaf(r.axs, sf, r.ax0);
        float gy = fmaf(r.ays, sf, r.ay0);
        float gz = fmaf(r.azs, sf, r.az0);
        gx = fminf(fmaxf(gx, 0.0f), 126.9995f);
        gy = fminf(fmaxf(gy, 0.0f), 126.9995f);
        gz = fminf(fmaxf(gz, 0.0f), 126.9995f);
        const float xbf = floorf(gx);
        const float ybf = floorf(gy);
        const float zbf = floorf(gz);
        const float fx = gx - xbf, fy = gy - ybf, fz = gz - zbf;
        const unsigned off = (unsigned)fmaf(zbf, 16384.0f, fmaf(ybf, 128.0f, xbf));

        const float* p0 = vol + off;
        const float2 v00 = *reinterpret_cast<const float2*>(p0);
        const float2 v01 = *reinterpret_cast<const float2*>(p0 + VOLN);
        const float2 v10 = *reinterpret_cast<const float2*>(p0 + VOLN * VOLN);
        const float2 v11 = *reinterpret_cast<const float2*>(p0 + VOLN * VOLN + VOLN);

        const float c00 = fmaf(fx, v00.y - v00.x, v00.x);
        const float c01 = fmaf(fx, v01.y - v01.x, v01.x);
        const float c10 = fmaf(fx, v10.y - v10.x, v10.x);
        const float c11 = fmaf(fx, v11.y - v11.x, v11.x);
        const float c0 = fmaf(fy, c01 - c00, c00);
        const float c1 = fmaf(fy, c11 - c10, c10);
        const float dens = fmaf(fz, c1 - c0, c0);

        const float w = __expf(dens);
        lsum += w;
        sacc = fmaf(sf, w, sacc);

        if (s < 6) d6 += dens;
        const bool o = (sf < r.sLo) || (sf > r.sHi);
        dout += o ? dens : 0.0f;
    }

    depth_low[view * NPIX + row * WLOW + t] =
        fmaf(r.zstep, sacc / lsum, r.z0) * r.ncz;

    __shared__ float s0[BLK], s1[BLK], s2[BLK];
    s0[t] = d6; s1[t] = dout; s2[t] = cnt;
    __syncthreads();
    for (int off = BLK / 2; off > 0; off >>= 1) {
        if (t < off) {
            s0[t] += s0[t + off];
            s1[t] += s1[t + off];
            s2[t] += s2[t + off];
        }
        __syncthreads();
    }
    if (t == 0) {
        partials[blockIdx.x * 3 + 0] = s0[0];
        partials[blockIdx.x * 3 + 1] = s1[0];
        partials[blockIdx.x * 3 + 2] = s2[0];
    }
}

// ---------------- fused epilogue: upsample (2 px/thread) + occ reduce ----
__global__ __launch_bounds__(BLK) void epilogue_kernel(
    const float* __restrict__ low, const float* __restrict__ partials,
    float* __restrict__ out)
{
    if (blockIdx.x >= UPS2_BLOCKS) {
        const int view = blockIdx.x - UPS2_BLOCKS;
        const int t = threadIdx.x;
        __shared__ float s0[BLK], s1[BLK], s2[BLK];
        const int bi = view * BLOCKS_PER_VIEW + t; // BLOCKS_PER_VIEW == BLK
        s0[t] = partials[bi * 3 + 0];
        s1[t] = partials[bi * 3 + 1];
        s2[t] = partials[bi * 3 + 2];
        __syncthreads();
        for (int off = BLK / 2; off > 0; off >>= 1) {
            if (t < off) {
                s0[t] += s0[t + off];
                s1[t] += s1[t + off];
                s2[t] += s2[t + off];
            }
            __syncthreads();
        }
        if (t == 0) {
            out[NVIEW * IMGH * IMGW + view] =
                s0[0] * (1.0f / (float)(NPIX * 6)) + s1[0] / (s2[0] + 1e-10f);
        }
        return;
    }

    const int idx2 = blockIdx.x * BLK + threadIdx.x;
    const int view = idx2 / (IMGH * IMGW / 2);
    const int rem  = idx2 - view * (IMGH * IMGW / 2);
    const int rr = rem >> 8;
    const int cp = rem & 255;
    const int cc0 = cp * 2;

    const float sy = (float)rr * 0.5f - 0.25f;
    const float y0f = floorf(sy);
    const float wy = sy - y0f;
    const int y0 = (int)y0f;
    const int y0c = max(y0, 0), y1c = min(y0 + 1, HLOW - 1);
    const float* src = low + view * NPIX;
    const float* r0 = src + y0c * WLOW;
    const float* r1 = src + y1c * WLOW;

    float2 res;
    {
        const float sx = (float)cc0 * 0.5f - 0.25f;
        const float x0f = floorf(sx);
        const float wx = sx - x0f;
        const int x0 = (int)x0f;
        const int x0c = max(x0, 0), x1c = min(x0 + 1, WLOW - 1);
        const float top = r0[x0c] * (1.0f - wx) + r0[x1c] * wx;
        const float bot = r1[x0c] * (1.0f - wx) + r1[x1c] * wx;
        res.x = top * (1.0f - wy) + bot * wy;
    }
    {
        const int cc1 = cc0 + 1;
        const float sx = (float)cc1 * 0.5f - 0.25f;
        const float x0f = floorf(sx);
        const float wx = sx - x0f;
        const int x0 = (int)x0f;
        const int x0c = max(x0, 0), x1c = min(x0 + 1, WLOW - 1);
        const float top = r0[x0c] * (1.0f - wx) + r0[x1c] * wx;
        const float bot = r1[x0c] * (1.0f - wx) + r1[x1c] * wx;
        res.y = top * (1.0f - wy) + bot * wy;
    }
    *reinterpret_cast<float2*>(out + view * (IMGH * IMGW) + rr * IMGW + cc0) = res;
}

extern "C" void kernel_launch(void* const* d_in, const int* in_sizes, int n_in,
                              void* d_out, int out_size, void* d_ws, size_t ws_size,
                              hipStream_t stream) {
    // input order: imgs, intrs, c2ws, near_fars, density_volume, stage_idx
    const float* intrs = (const float*)d_in[1];
    const float* c2ws  = (const float*)d_in[2];
    const float* nf    = (const float*)d_in[3];
    const float* vol   = (const float*)d_in[4];
    float* out = (float*)d_out;

    const size_t pack_bytes  = (size_t)NVOX * 8 + 16;   // +16: x=126 load tail
    const size_t depth_bytes = (size_t)NVIEW * NPIX * 4;
    const size_t part_bytes  = (size_t)NVIEW * BLOCKS_PER_VIEW * 3 * 4;
    char* ws = (char*)d_ws;

    float* depth_low;
    float* partials;

    if (ws_size >= pack_bytes + depth_bytes + part_bytes) {
        uint2* P = (uint2*)ws;
        depth_low = (float*)(ws + pack_bytes);
        partials  = depth_low + NVIEW * NPIX;
        build_pack8_kernel<<<NVOX / BLK, BLK, 0, stream>>>(vol, P);
        raymarch_pack8_kernel<<<MARCH_BLOCKS, BLK, 0, stream>>>(
            intrs, c2ws, nf, (const char*)ws, depth_low, partials);
    } else {
        depth_low = (float*)ws;
        partials  = depth_low + NVIEW * NPIX;
        raymarch_f32_kernel<<<MARCH_BLOCKS, BLK, 0, stream>>>(
            intrs, c2ws, nf, vol, depth_low, partials);
    }

    epilogue_kernel<<<UPS2_BLOCKS + NVIEW, BLK, 0, stream>>>(depth_low, partials, out);
}